// Round 7
// baseline (158.271 us; speedup 1.0000x reference)
//
#include <hip/hip_runtime.h>
#include <math.h>

#define BB 512   // batch
#define LL 512   // seq len
#define VV 23757 // wd vocab
#define PP 57    // pos vocab

#define L2E  1.4426950408889634f
#define NL2E (-1.4426950408889634f)
#define TL2E 2.8853900817779268f   // 2*log2(e)

__device__ __forceinline__ float rcp_(float x) { return __builtin_amdgcn_rcpf(x); }
__device__ __forceinline__ float exp2_(float x) { return __builtin_amdgcn_exp2f(x); }
__device__ __forceinline__ float tanh_(float x) { return 1.f - 2.f * rcp_(exp2_(TL2E * x) + 1.f); }

// gate scale: r,z -> -log2e ; n -> 2*log2e   (dg = dir*9 + g*3 + j, gate-major)
__device__ __forceinline__ float gscale(int dg) {
    int g = (dg % 9) / 3;
    return g == 2 ? TL2E : NL2E;
}
__device__ __forceinline__ int is_rz(int dg) { return ((dg % 9) / 3) < 2; }
// permute gate-major dg -> unit-major index [dir][j][g]
__device__ __forceinline__ int permdg(int dg) {
    int dirx = dg / 9, rem = dg % 9, g = rem / 3, j = rem % 3;
    return dirx * 9 + j * 3 + g;
}

// quad_perm broadcast of lane K (0..2) within each 4-lane group, via DPP.
template <int K>
__device__ __forceinline__ float qb(float x) {
    constexpr int ctrl = K * 0x55;
    return __int_as_float(__builtin_amdgcn_update_dpp(0, __float_as_int(x), ctrl, 0xF, 0xF, true));
}

struct F3 { float r, z, n; };

// ---------------------------------------------------------------------------
// 1. Tables. E raw [dg][tap][d]; beff/Gp PERMUTED to [dir][j][g] order and
//    prescaled; wih1t/bih1t gate-major prescaled (consumed per-row by scan1).
// ---------------------------------------------------------------------------
__global__ void k_build_tables(const float* __restrict__ wd_wih0, const float* __restrict__ wd_bih0,
                               const float* __restrict__ wd_bhh0,
                               const float* __restrict__ cw2, const float* __restrict__ cb2,
                               const float* __restrict__ cw3, const float* __restrict__ cb3,
                               const float* __restrict__ cw4, const float* __restrict__ cb4,
                               const float* __restrict__ pos_emb,
                               const float* __restrict__ pos_wih0, const float* __restrict__ pos_bih0,
                               const float* __restrict__ pos_bhh0,
                               const float* __restrict__ wd_wih1, const float* __restrict__ wd_bih1,
                               const float* __restrict__ wd_bhh1,
                               const float* __restrict__ pos_wih1, const float* __restrict__ pos_bih1,
                               const float* __restrict__ pos_bhh1,
                               float* __restrict__ E, float* __restrict__ beff, float* __restrict__ Gp,
                               float* __restrict__ wih1t, float* __restrict__ bih1t)
{
    int idx = blockIdx.x * blockDim.x + threadIdx.x;
    if (idx < 7200) {
        int d  = idx % 100;
        int tt = (idx / 100) % 4;
        int dg = idx / 400;
        const float* wih = wd_wih0 + dg * 144;
        float acc = 0.f;
        if (tt == 0) {        // offset -2
            for (int o = 0; o < 48; ++o) acc += wih[96 + o] * cw4[o * 400 + d * 4 + 0];
        } else if (tt == 1) { // offset -1
            for (int o = 0; o < 48; ++o) acc += wih[o]      * cw2[o * 200 + d * 2 + 0];
            for (int o = 0; o < 48; ++o) acc += wih[48 + o] * cw3[o * 300 + d * 3 + 0];
            for (int o = 0; o < 48; ++o) acc += wih[96 + o] * cw4[o * 400 + d * 4 + 1];
        } else if (tt == 2) { // offset 0
            for (int o = 0; o < 48; ++o) acc += wih[o]      * cw2[o * 200 + d * 2 + 1];
            for (int o = 0; o < 48; ++o) acc += wih[48 + o] * cw3[o * 300 + d * 3 + 1];
            for (int o = 0; o < 48; ++o) acc += wih[96 + o] * cw4[o * 400 + d * 4 + 2];
        } else {              // offset +1
            for (int o = 0; o < 48; ++o) acc += wih[48 + o] * cw3[o * 300 + d * 3 + 2];
            for (int o = 0; o < 48; ++o) acc += wih[96 + o] * cw4[o * 400 + d * 4 + 3];
        }
        E[idx] = acc;
    } else if (idx < 7218) {
        int dg = idx - 7200;
        float acc = wd_bih0[dg];
        for (int o = 0; o < 48; ++o) acc += wd_wih0[dg * 144 + o]      * cb2[o];
        for (int o = 0; o < 48; ++o) acc += wd_wih0[dg * 144 + 48 + o] * cb3[o];
        for (int o = 0; o < 48; ++o) acc += wd_wih0[dg * 144 + 96 + o] * cb4[o];
        if (is_rz(dg)) acc += wd_bhh0[dg];
        beff[permdg(dg)] = gscale(dg) * acc;
    } else if (idx < 8244) {
        int k = idx - 7218;
        int dg = k % 18;
        int p  = k / 18;
        float acc = pos_bih0[dg];
        for (int d = 0; d < 100; ++d) acc += pos_emb[p * 100 + d] * pos_wih0[dg * 100 + d];
        if (is_rz(dg)) acc += pos_bhh0[dg];
        Gp[p * 18 + permdg(dg)] = gscale(dg) * acc;
    } else if (idx < 8352) {
        int i = idx - 8244; int dg = i / 6;
        wih1t[i] = gscale(dg) * wd_wih1[i];
    } else if (idx < 8370) {
        int dg = idx - 8352;
        float a = wd_bih1[dg] + (is_rz(dg) ? wd_bhh1[dg] : 0.f);
        bih1t[dg] = gscale(dg) * a;
    } else if (idx < 8478) {
        int i = idx - 8370; int dg = i / 6;
        wih1t[108 + i] = gscale(dg) * pos_wih1[i];
    } else if (idx < 8496) {
        int dg = idx - 8478;
        float a = pos_bih1[dg] + (is_rz(dg) ? pos_bhh1[dg] : 0.f);
        bih1t[18 + dg] = gscale(dg) * a;
    }
}

// ---------------------------------------------------------------------------
// 2. P[v][tap][dir][j][g] = s_g * (wd_emb[v,:] . E[dg][tap][:])  (permuted!)
//    + zero-row at v=VV for OOB taps.
// ---------------------------------------------------------------------------
__global__ void __launch_bounds__(256) k_build_P(const float* __restrict__ wd_emb,
                                                 const float* __restrict__ E,
                                                 float* __restrict__ P)
{
    __shared__ float sEt[7200]; // [d][r], r = tt*18+dg (gate-major)
    int T = blockIdx.x * 256 + threadIdx.x;
    if (T < 72) P[(size_t)VV * 72 + T] = 0.f;   // zero row
    for (int i = threadIdx.x; i < 7200; i += 256) {
        int d = i % 100, r = i / 100;
        int tt = r / 18, dg = r % 18;
        sEt[d * 72 + r] = E[dg * 400 + tt * 100 + d];
    }
    __syncthreads();
    int og = T & 7;
    int vb = T >> 3;
    int v0 = vb * 4;
    if (v0 >= VV) return;
    int vlim = VV - 1 - v0;  // max usable vi
    float gs[9];
    int po[9];
#pragma unroll
    for (int k = 0; k < 9; ++k) {
        int r = og * 9 + k;
        int tt = r / 18, dg = r % 18;
        gs[k] = gscale(dg);
        po[k] = tt * 18 + permdg(dg);
    }
    float acc[4][9];
#pragma unroll
    for (int vi = 0; vi < 4; ++vi)
#pragma unroll
        for (int k = 0; k < 9; ++k) acc[vi][k] = 0.f;

    const float* e0 = wd_emb + (size_t)v0 * 100;
#pragma unroll 1
    for (int d4 = 0; d4 < 25; ++d4) {
        float4 ev[4];
#pragma unroll
        for (int vi = 0; vi < 4; ++vi) {
            int vv = vi <= vlim ? vi : vlim;
            ev[vi] = *(const float4*)(e0 + vv * 100 + d4 * 4);
        }
#pragma unroll
        for (int dd = 0; dd < 4; ++dd) {
            int d = d4 * 4 + dd;
            const float* et = sEt + d * 72 + og * 9;
            float em0 = ((const float*)&ev[0])[dd];
            float em1 = ((const float*)&ev[1])[dd];
            float em2 = ((const float*)&ev[2])[dd];
            float em3 = ((const float*)&ev[3])[dd];
#pragma unroll
            for (int k = 0; k < 9; ++k) {
                float e = et[k];
                acc[0][k] = fmaf(em0, e, acc[0][k]);
                acc[1][k] = fmaf(em1, e, acc[1][k]);
                acc[2][k] = fmaf(em2, e, acc[2][k]);
                acc[3][k] = fmaf(em3, e, acc[3][k]);
            }
        }
    }
#pragma unroll
    for (int vi = 0; vi < 4; ++vi) {
        if (vi <= vlim) {
            float* p = P + (size_t)(v0 + vi) * 72;
#pragma unroll
            for (int k = 0; k < 9; ++k) p[po[k]] = gs[k] * acc[vi][k];
        }
    }
}

// ---------------------------------------------------------------------------
// 3. Scan layer 0 with FUSED gather. Block = 1 chain x 16 chunks x 4 lanes.
//    Chunk c: t = 32c-48+i, i in [0,80); stores only i in [48,80).
//    Two-stage pipeline: idx loads 16 ahead -> P gathers 8 ahead -> consume.
//    out layout: [chain][l][4].
// ---------------------------------------------------------------------------
__global__ void __launch_bounds__(64) k_scan0(
        const int* __restrict__ wd, const int* __restrict__ pos,
        const float* __restrict__ P, const float* __restrict__ beffp,
        const float* __restrict__ Gp, float* __restrict__ out,
        const float* __restrict__ whhA, const float* __restrict__ bhhA,
        const float* __restrict__ whhB, const float* __restrict__ bhhB)
{
    __shared__ float lbuf[16 * 81];
    int lane = threadIdx.x;
    int c = lane >> 2, sub = lane & 3;
    int jj = sub < 3 ? sub : 2;
    int chain = blockIdx.x;
    int branch = chain >> 10;
    int rem = chain & 1023;
    int dir = rem >> 9;
    int b = rem & 511;

    const float* whh = (branch ? whhB : whhA) + dir * 27;
    const float* bhh = (branch ? bhhB : bhhA) + dir * 9;

    float wr0 = NL2E * whh[jj * 3 + 0], wr1 = NL2E * whh[jj * 3 + 1], wr2 = NL2E * whh[jj * 3 + 2];
    float wz0 = NL2E * whh[(3 + jj) * 3 + 0], wz1 = NL2E * whh[(3 + jj) * 3 + 1], wz2 = NL2E * whh[(3 + jj) * 3 + 2];
    float wn0 = TL2E * whh[(6 + jj) * 3 + 0], wn1 = TL2E * whh[(6 + jj) * 3 + 1], wn2 = TL2E * whh[(6 + jj) * 3 + 2];
    float bnx = TL2E * bhh[6 + jj];

    int t0 = c * 32 - 48;
    char* ob = (char*)out + (size_t)chain * (LL * 16) + sub * 64;
    int coff = (dir * 9 + jj * 3) * 4;       // byte offset of this lane's 3 gates
    const char* Pc = (const char*)P;
    float h = 0.f;

    auto lof = [&](int t) { int tc = t < 0 ? 0 : (t > 511 ? 511 : t); return dir ? (511 - tc) : tc; };

#define GRU_BODY(GR, GZ, GN)                                                  \
    {                                                                         \
        float h0 = qb<0>(h), h1 = qb<1>(h), h2 = qb<2>(h);                    \
        float hm1 = h - 1.f;                                                  \
        float sr = fmaf(wr0, h0, (GR)) + fmaf(wr1, h1, wr2 * h2);             \
        float sz = fmaf(wz0, h0, (GZ)) + fmaf(wz1, h1, wz2 * h2);             \
        float gn3 = fmaf(wn0, h0, fmaf(wn1, h1, fmaf(wn2, h2, bnx)));         \
        float r = rcp_(1.f + exp2_(sr));                                      \
        float z = rcp_(1.f + exp2_(sz));                                      \
        float y2 = fmaf(r, gn3, (GN));                                        \
        float u = rcp_(1.f + exp2_(y2));                                      \
        float a = fmaf(2.f, u, hm1);                                          \
        float n = fmaf(-2.f, u, 1.f);                                         \
        float hn = fmaf(z, a, n);                                             \
        h = (t >= 0) ? hn : 0.f;                                              \
        lbuf[(s)*81 + c * 5 + sub] = h;                                       \
    }

#define FLUSH(NS)                                                             \
    __syncthreads();                                                          \
    if (g >= 3) {                                                             \
        int tbase = t0 + g * 16;                                              \
        int l0 = dir ? (LL - 1 - tbase - 15) : tbase;                         \
        _Pragma("unroll")                                                     \
        for (int i = 0; i < 4; ++i) {                                         \
            int lofs = sub * 4 + i;                                           \
            int s2 = dir ? (15 - lofs) : lofs;                                \
            float4 vv4;                                                       \
            vv4.x = lbuf[s2 * 81 + c * 5 + 0];                                \
            vv4.y = lbuf[s2 * 81 + c * 5 + 1];                                \
            vv4.z = lbuf[s2 * 81 + c * 5 + 2];                                \
            vv4.w = lbuf[s2 * 81 + c * 5 + 3];                                \
            *(float4*)(ob + (size_t)l0 * 16 + i * 16) = vv4;                  \
        }                                                                     \
    }                                                                         \
    __syncthreads();

    if (branch == 0) {
        const int* row = wd + b * LL;
        float be0 = beffp[dir * 9 + jj * 3 + 0];
        float be1 = beffp[dir * 9 + jj * 3 + 1];
        float be2 = beffp[dir * 9 + jj * 3 + 2];
        int4 vb_[8];
        F3 gb_[8][4];
#pragma unroll
        for (int s = 0; s < 8; ++s) {   // indices for steps t0..t0+7
            int l = lof(t0 + s);
            int4 vv;
            vv.x = (l >= 2) ? row[l - 2] : VV;
            vv.y = (l >= 1) ? row[l - 1] : VV;
            vv.z = row[l];
            vv.w = (l <= 510) ? row[l + 1] : VV;
            vb_[s] = vv;
        }
#pragma unroll
        for (int s = 0; s < 8; ++s) {   // gathers for steps t0..t0+7
            int4 vv = vb_[s];
            gb_[s][0] = *(const F3*)(Pc + (unsigned)vv.x * 288u + 0 + coff);
            gb_[s][1] = *(const F3*)(Pc + (unsigned)vv.y * 288u + 72 + coff);
            gb_[s][2] = *(const F3*)(Pc + (unsigned)vv.z * 288u + 144 + coff);
            gb_[s][3] = *(const F3*)(Pc + (unsigned)vv.w * 288u + 216 + coff);
        }
#pragma unroll
        for (int s = 0; s < 8; ++s) {   // indices for steps t0+8..t0+15
            int l = lof(t0 + 8 + s);
            int4 vv;
            vv.x = (l >= 2) ? row[l - 2] : VV;
            vv.y = (l >= 1) ? row[l - 1] : VV;
            vv.z = row[l];
            vv.w = (l <= 510) ? row[l + 1] : VV;
            vb_[s] = vv;
        }
        for (int g = 0; g < 5; ++g) {
#pragma unroll
            for (int s = 0; s < 16; ++s) {
                int t = t0 + g * 16 + s;
                int sl = s & 7;
                F3 a0 = gb_[sl][0], a1 = gb_[sl][1], a2 = gb_[sl][2], a3 = gb_[sl][3];
                int4 vv = vb_[sl];
                gb_[sl][0] = *(const F3*)(Pc + (unsigned)vv.x * 288u + 0 + coff);
                gb_[sl][1] = *(const F3*)(Pc + (unsigned)vv.y * 288u + 72 + coff);
                gb_[sl][2] = *(const F3*)(Pc + (unsigned)vv.z * 288u + 144 + coff);
                gb_[sl][3] = *(const F3*)(Pc + (unsigned)vv.w * 288u + 216 + coff);
                {
                    int l = lof(t + 16);
                    int4 nv;
                    nv.x = (l >= 2) ? row[l - 2] : VV;
                    nv.y = (l >= 1) ? row[l - 1] : VV;
                    nv.z = row[l];
                    nv.w = (l <= 510) ? row[l + 1] : VV;
                    vb_[sl] = nv;
                }
                float gr = be0 + a0.r + a1.r + a2.r + a3.r;
                float gz = be1 + a0.z + a1.z + a2.z + a3.z;
                float gnv = be2 + a0.n + a1.n + a2.n + a3.n;
                GRU_BODY(gr, gz, gnv)
            }
            FLUSH(16)
        }
    } else {
        const int* prow = pos + b * LL;
        int pb_[8];
        F3 gb_[8];
#pragma unroll
        for (int s = 0; s < 8; ++s) pb_[s] = prow[lof(t0 + s)];
#pragma unroll
        for (int s = 0; s < 8; ++s)
            gb_[s] = *(const F3*)((const char*)Gp + (unsigned)pb_[s] * 72u + coff);
#pragma unroll
        for (int s = 0; s < 8; ++s) pb_[s] = prow[lof(t0 + 8 + s)];
        for (int g = 0; g < 5; ++g) {
#pragma unroll
            for (int s = 0; s < 16; ++s) {
                int t = t0 + g * 16 + s;
                int sl = s & 7;
                F3 a0 = gb_[sl];
                int pv = pb_[sl];
                gb_[sl] = *(const F3*)((const char*)Gp + (unsigned)pv * 72u + coff);
                pb_[sl] = prow[lof(t + 16)];
                GRU_BODY(a0.r, a0.z, a0.n)
            }
            FLUSH(16)
        }
    }
#undef GRU_BODY
#undef FLUSH
}

// ---------------------------------------------------------------------------
// 4. Scan layer 1 with fused input projection. 32 chunks/chain, 16 real +
//    48 warm (64 steps). 2 blocks per chain; 4096 blocks total.
// ---------------------------------------------------------------------------
__global__ void __launch_bounds__(64) k_scan1(
        const float* __restrict__ out0, float* __restrict__ out1,
        const float* __restrict__ whhA, const float* __restrict__ bhhA,
        const float* __restrict__ whhB, const float* __restrict__ bhhB,
        const float* __restrict__ wih1t, const float* __restrict__ bih1t)
{
    __shared__ float lbuf[8 * 81];
    int lane = threadIdx.x;
    int c = lane >> 2, sub = lane & 3;
    int jj = sub < 3 ? sub : 2;
    int chain = blockIdx.x >> 1;
    int ck = ((blockIdx.x & 1) << 4) + c;   // chunk 0..31
    int branch = chain >> 10;
    int rem = chain & 1023;
    int dir = rem >> 9;
    int b = rem & 511;

    const float* whh = (branch ? whhB : whhA) + dir * 27;
    const float* bhh = (branch ? bhhB : bhhA) + dir * 9;

    float wr0 = NL2E * whh[jj * 3 + 0], wr1 = NL2E * whh[jj * 3 + 1], wr2 = NL2E * whh[jj * 3 + 2];
    float wz0 = NL2E * whh[(3 + jj) * 3 + 0], wz1 = NL2E * whh[(3 + jj) * 3 + 1], wz2 = NL2E * whh[(3 + jj) * 3 + 2];
    float wn0 = TL2E * whh[(6 + jj) * 3 + 0], wn1 = TL2E * whh[(6 + jj) * 3 + 1], wn2 = TL2E * whh[(6 + jj) * 3 + 2];
    float bnx = TL2E * bhh[6 + jj];

    const float* Wb = wih1t + branch * 108;
    const float* Bv = bih1t + branch * 18;
    int dgr = dir * 9 + jj, dgz = dgr + 3, dgn = dgr + 6;
    float Wr[6], Wz[6], Wn[6];
#pragma unroll
    for (int q = 0; q < 6; ++q) {
        Wr[q] = Wb[dgr * 6 + q];
        Wz[q] = Wb[dgz * 6 + q];
        Wn[q] = Wb[dgn * 6 + q];
    }
    float Br = Bv[dgr], Bz = Bv[dgz], Bn = Bv[dgn];

    const float4* o0 = (const float4*)out0 + (size_t)((branch * 2 + 0) * BB + b) * LL;
    const float4* o1 = (const float4*)out0 + (size_t)((branch * 2 + 1) * BB + b) * LL;

    int t0 = ck * 16 - 48;
    auto lof = [&](int t) { int tc = t < 0 ? 0 : (t > 511 ? 511 : t); return dir ? (511 - tc) : tc; };

    float4 bf[8], bg[8];
#pragma unroll
    for (int s = 0; s < 8; ++s) {
        int l = lof(t0 + s);
        bf[s] = o0[l]; bg[s] = o1[l];
    }
    int pft = t0 + 8;

    char* ob = (char*)out1 + (size_t)chain * (LL * 16) + sub * 32;

    float h = 0.f;
    for (int g = 0; g < 8; ++g) {
#pragma unroll
        for (int s = 0; s < 8; ++s) {
            int t = t0 + g * 8 + s;
            float4 f4 = bf[s], q4 = bg[s];
            int lpf = lof(pft);
            bf[s] = o0[lpf]; bg[s] = o1[lpf];
            ++pft;

            float gr = Br, gz = Bz, gn = Bn;
            gr = fmaf(f4.x, Wr[0], gr); gr = fmaf(f4.y, Wr[1], gr); gr = fmaf(f4.z, Wr[2], gr);
            gr = fmaf(q4.x, Wr[3], gr); gr = fmaf(q4.y, Wr[4], gr); gr = fmaf(q4.z, Wr[5], gr);
            gz = fmaf(f4.x, Wz[0], gz); gz = fmaf(f4.y, Wz[1], gz); gz = fmaf(f4.z, Wz[2], gz);
            gz = fmaf(q4.x, Wz[3], gz); gz = fmaf(q4.y, Wz[4], gz); gz = fmaf(q4.z, Wz[5], gz);
            gn = fmaf(f4.x, Wn[0], gn); gn = fmaf(f4.y, Wn[1], gn); gn = fmaf(f4.z, Wn[2], gn);
            gn = fmaf(q4.x, Wn[3], gn); gn = fmaf(q4.y, Wn[4], gn); gn = fmaf(q4.z, Wn[5], gn);

            float h0 = qb<0>(h), h1 = qb<1>(h), h2 = qb<2>(h);
            float hm1 = h - 1.f;
            float sr = fmaf(wr0, h0, gr) + fmaf(wr1, h1, wr2 * h2);
            float sz = fmaf(wz0, h0, gz) + fmaf(wz1, h1, wz2 * h2);
            float gn3 = fmaf(wn0, h0, fmaf(wn1, h1, fmaf(wn2, h2, bnx)));
            float r = rcp_(1.f + exp2_(sr));
            float z = rcp_(1.f + exp2_(sz));
            float y2 = fmaf(r, gn3, gn);
            float u = rcp_(1.f + exp2_(y2));
            float a = fmaf(2.f, u, hm1);
            float n = fmaf(-2.f, u, 1.f);
            float hn = fmaf(z, a, n);
            h = (t >= 0) ? hn : 0.f;
            lbuf[s * 81 + c * 5 + sub] = h;
        }
        __syncthreads();
        if (g >= 6) {
            int tbase = t0 + g * 8;
            int l0 = dir ? (LL - 1 - tbase - 7) : tbase;
#pragma unroll
            for (int i = 0; i < 2; ++i) {
                int lofs = sub * 2 + i;
                int s = dir ? (7 - lofs) : lofs;
                float4 vv;
                vv.x = lbuf[s * 81 + c * 5 + 0];
                vv.y = lbuf[s * 81 + c * 5 + 1];
                vv.z = lbuf[s * 81 + c * 5 + 2];
                vv.w = lbuf[s * 81 + c * 5 + 3];
                *(float4*)(ob + (size_t)l0 * 16 + i * 16) = vv;
            }
        }
        __syncthreads();
    }
}

// ---------------------------------------------------------------------------
// 5. Fused head: attention over wd_out + posfc/auxi + fc1/fc2 softmax.
// ---------------------------------------------------------------------------
__global__ void k_head(const float* __restrict__ out1,
                       const float* __restrict__ sw, const float* __restrict__ ap,
                       const float* __restrict__ pg, const float* __restrict__ pb,
                       const float* __restrict__ pw, const float* __restrict__ pbias,
                       const float* __restrict__ f1w, const float* __restrict__ f1b,
                       const float* __restrict__ fg, const float* __restrict__ fb,
                       const float* __restrict__ f2w, const float* __restrict__ f2b,
                       float* __restrict__ out)
{
    int b = blockIdx.x;
    int lane = threadIdx.x;
    __shared__ float ssw[36], sap[6], sph[6], scomb[9], sh[128], sl[6], se[6];
    const float BN = 0.9999950000374997f; // 1/sqrt(1+1e-5)

    if (lane < 36) ssw[lane] = sw[lane];
    if (lane < 6) {
        sap[lane] = ap[lane];
        const float* posf = out1 + (size_t)((2 * BB) + b) * LL * 4 + 511 * 4;
        const float* posb = out1 + (size_t)((3 * BB) + b) * LL * 4 + 511 * 4;
        float v = lane < 3 ? posf[lane] : posb[lane - 3];
        float x = v * BN * pg[lane] + pb[lane];
        sph[lane] = fmaxf(x, 0.f);
    }
    __syncthreads();

    const float* F = out1 + (size_t)b * LL * 4;
    const float* Bw = out1 + (size_t)(BB + b) * LL * 4;

    float att[8];
    float mx = -1e30f;
#pragma unroll
    for (int k = 0; k < 8; ++k) {
        int l = lane + 64 * k;
        float4 f4 = *(const float4*)(F + l * 4);
        float4 b4 = *(const float4*)(Bw + l * 4);
        float r0 = f4.x, r1 = f4.y, r2 = f4.z, r3 = b4.x, r4 = b4.y, r5 = b4.z;
        float a = 0.f;
#pragma unroll
        for (int j = 0; j < 6; ++j) {
            float s = r0 * ssw[0 * 6 + j] + r1 * ssw[1 * 6 + j] + r2 * ssw[2 * 6 + j] +
                      r3 * ssw[3 * 6 + j] + r4 * ssw[4 * 6 + j] + r5 * ssw[5 * 6 + j];
            a += sap[j] * tanh_(s);
        }
        att[k] = a;
        mx = fmaxf(mx, a);
    }
#pragma unroll
    for (int off = 32; off; off >>= 1) mx = fmaxf(mx, __shfl_xor(mx, off));
    float e[8];
    float sum = 0.f;
#pragma unroll
    for (int k = 0; k < 8; ++k) { e[k] = exp2_(L2E * (att[k] - mx)); sum += e[k]; }
#pragma unroll
    for (int off = 32; off; off >>= 1) sum += __shfl_xor(sum, off);

    float acc[6] = {0.f, 0.f, 0.f, 0.f, 0.f, 0.f};
#pragma unroll
    for (int k = 0; k < 8; ++k) {
        int l = lane + 64 * k;
        float4 f4 = *(const float4*)(F + l * 4);
        float4 b4 = *(const float4*)(Bw + l * 4);
        acc[0] += e[k] * f4.x; acc[1] += e[k] * f4.y; acc[2] += e[k] * f4.z;
        acc[3] += e[k] * b4.x; acc[4] += e[k] * b4.y; acc[5] += e[k] * b4.z;
    }
#pragma unroll
    for (int j = 0; j < 6; ++j) {
#pragma unroll
        for (int off = 32; off; off >>= 1) acc[j] += __shfl_xor(acc[j], off);
    }
    if (lane < 6) scomb[lane] = acc[lane] / sum;
    __syncthreads();

    if (lane == 0) {
        float a[3];
#pragma unroll
        for (int j = 0; j < 3; ++j) {
            float t = pbias[j];
#pragma unroll
            for (int i = 0; i < 6; ++i) t += sph[i] * pw[j * 6 + i];
            a[j] = t;
        }
        float m = fmaxf(a[0], fmaxf(a[1], a[2]));
        float e0 = exp2_(L2E * (a[0] - m)), e1 = exp2_(L2E * (a[1] - m)), e2 = exp2_(L2E * (a[2] - m));
        float s = e0 + e1 + e2;
        float x0 = e0 / s, x1 = e1 / s, x2 = e2 / s;
        scomb[6] = x0; scomb[7] = x1; scomb[8] = x2;
        out[BB * 6 + b * 3 + 0] = x0;
        out[BB * 6 + b * 3 + 1] = x1;
        out[BB * 6 + b * 3 + 2] = x2;
    }
    __syncthreads();
    for (int o = lane; o < 128; o += 64) {
        float t = f1b[o];
#pragma unroll
        for (int k = 0; k < 9; ++k) t += scomb[k] * f1w[o * 9 + k];
        float x = t * BN * fg[o] + fb[o];
        sh[o] = fmaxf(x, 0.f);
    }
    __syncthreads();
    if (lane < 6) {
        float t = f2b[lane];
        for (int k = 0; k < 128; ++k) t += sh[k] * f2w[lane * 128 + k];
        sl[lane] = t;
    }
    __syncthreads();
    if (lane < 6) {
        float m = sl[0];
#pragma unroll
        for (int j = 1; j < 6; ++j) m = fmaxf(m, sl[j]);
        se[lane] = exp2_(L2E * (sl[lane] - m));
    }
    __syncthreads();
    if (lane < 6) {
        float s = se[0] + se[1] + se[2] + se[3] + se[4] + se[5];
        out[b * 6 + lane] = se[lane] / s;
    }
}

// ---------------------------------------------------------------------------
extern "C" void kernel_launch(void* const* d_in, const int* in_sizes, int n_in,
                              void* d_out, int out_size, void* d_ws, size_t ws_size,
                              hipStream_t stream)
{
    const int* wd  = (const int*)d_in[0];
    const int* pos = (const int*)d_in[1];
    const float* wd_emb  = (const float*)d_in[2];
    const float* pos_emb = (const float*)d_in[3];
    const float* cw2 = (const float*)d_in[4];  const float* cb2 = (const float*)d_in[5];
    const float* cw3 = (const float*)d_in[6];  const float* cb3 = (const float*)d_in[7];
    const float* cw4 = (const float*)d_in[8];  const float* cb4 = (const float*)d_in[9];
    const float* wd_wih0 = (const float*)d_in[10]; const float* wd_whh0 = (const float*)d_in[11];
    const float* wd_bih0 = (const float*)d_in[12]; const float* wd_bhh0 = (const float*)d_in[13];
    const float* wd_wih1 = (const float*)d_in[14]; const float* wd_whh1 = (const float*)d_in[15];
    const float* wd_bih1 = (const float*)d_in[16]; const float* wd_bhh1 = (const float*)d_in[17];
    const float* pos_wih0 = (const float*)d_in[18]; const float* pos_whh0 = (const float*)d_in[19];
    const float* pos_bih0 = (const float*)d_in[20]; const float* pos_bhh0 = (const float*)d_in[21];
    const float* pos_wih1 = (const float*)d_in[22]; const float* pos_whh1 = (const float*)d_in[23];
    const float* pos_bih1 = (const float*)d_in[24]; const float* pos_bhh1 = (const float*)d_in[25];
    const float* squish_w   = (const float*)d_in[26];
    const float* atten_proj = (const float*)d_in[27];
    const float* posfc_gamma = (const float*)d_in[28]; const float* posfc_beta = (const float*)d_in[29];
    const float* posfc_w = (const float*)d_in[30]; const float* posfc_b = (const float*)d_in[31];
    const float* fc1_w = (const float*)d_in[32]; const float* fc1_b = (const float*)d_in[33];
    const float* fc_gamma = (const float*)d_in[34]; const float* fc_beta = (const float*)d_in[35];
    const float* fc2_w = (const float*)d_in[36]; const float* fc2_b = (const float*)d_in[37];

    float* ws = (float*)d_ws;
    size_t off = 0;
    float* P = ws + off;      off += (size_t)VV * 72 + 80;       // + zero row
    float* out0 = ws + off;   off += (size_t)4 * BB * LL * 4;
    float* out1 = ws + off;   off += (size_t)4 * BB * LL * 4;
    float* Etab = ws + off;   off += 7200;
    float* beff = ws + off;   off += 32;
    float* Gp = ws + off;     off += PP * 18 + 14;
    float* wih1t = ws + off;  off += 216;
    float* bih1t = ws + off;  off += 40;

    k_build_tables<<<(8496 + 255) / 256, 256, 0, stream>>>(
        wd_wih0, wd_bih0, wd_bhh0, cw2, cb2, cw3, cb3, cw4, cb4,
        pos_emb, pos_wih0, pos_bih0, pos_bhh0,
        wd_wih1, wd_bih1, wd_bhh1, pos_wih1, pos_bih1, pos_bhh1,
        Etab, beff, Gp, wih1t, bih1t);
    {
        int vb = (VV + 3) / 4;
        int threads = vb * 8;
        k_build_P<<<(threads + 255) / 256, 256, 0, stream>>>(wd_emb, Etab, P);
    }
    k_scan0<<<2048, 64, 0, stream>>>(wd, pos, P, beff, Gp, out0,
                                     wd_whh0, wd_bhh0, pos_whh0, pos_bhh0);
    k_scan1<<<4096, 64, 0, stream>>>(out0, out1, wd_whh1, wd_bhh1, pos_whh1, pos_bhh1,
                                     wih1t, bih1t);
    k_head<<<BB, 64, 0, stream>>>(out1, squish_w, atten_proj, posfc_gamma, posfc_beta,
                                  posfc_w, posfc_b, fc1_w, fc1_b, fc_gamma, fc_beta,
                                  fc2_w, fc2_b, (float*)d_out);
}

// Round 8
// 138.004 us; speedup vs baseline: 1.1469x; 1.1469x over previous
//
#include <hip/hip_runtime.h>
#include <math.h>

#define BB 512   // batch
#define LL 512   // seq len
#define VV 23757 // wd vocab
#define PP 57    // pos vocab

#define L2E  1.4426950408889634f
#define NL2E (-1.4426950408889634f)
#define TL2E 2.8853900817779268f   // 2*log2(e)

__device__ __forceinline__ float rcp_(float x) { return __builtin_amdgcn_rcpf(x); }
__device__ __forceinline__ float exp2_(float x) { return __builtin_amdgcn_exp2f(x); }
__device__ __forceinline__ float tanh_(float x) { return 1.f - 2.f * rcp_(exp2_(TL2E * x) + 1.f); }

// gate scale: r,z -> -log2e ; n -> 2*log2e   (dg = dir*9 + g*3 + j)
__device__ __forceinline__ float gscale(int dg) {
    int g = (dg % 9) / 3;
    return g == 2 ? TL2E : NL2E;
}
__device__ __forceinline__ int is_rz(int dg) { return ((dg % 9) / 3) < 2; }

// quad_perm broadcast of lane K (0..2) within each 4-lane group, via DPP.
template <int K>
__device__ __forceinline__ float qb(float x) {
    constexpr int ctrl = K * 0x55;
    return __int_as_float(__builtin_amdgcn_update_dpp(0, __float_as_int(x), ctrl, 0xF, 0xF, true));
}

struct F3 { float r, z, n; };

// ---------------------------------------------------------------------------
// 1. Tables (prescaled for exp2-form gates), gate-major layouts (R6).
// ---------------------------------------------------------------------------
__global__ void k_build_tables(const float* __restrict__ wd_wih0, const float* __restrict__ wd_bih0,
                               const float* __restrict__ wd_bhh0,
                               const float* __restrict__ cw2, const float* __restrict__ cb2,
                               const float* __restrict__ cw3, const float* __restrict__ cb3,
                               const float* __restrict__ cw4, const float* __restrict__ cb4,
                               const float* __restrict__ pos_emb,
                               const float* __restrict__ pos_wih0, const float* __restrict__ pos_bih0,
                               const float* __restrict__ pos_bhh0,
                               const float* __restrict__ wd_wih1, const float* __restrict__ wd_bih1,
                               const float* __restrict__ wd_bhh1,
                               const float* __restrict__ pos_wih1, const float* __restrict__ pos_bih1,
                               const float* __restrict__ pos_bhh1,
                               float* __restrict__ E, float* __restrict__ beff, float* __restrict__ Gp,
                               float* __restrict__ wih1t, float* __restrict__ bih1t)
{
    int idx = blockIdx.x * blockDim.x + threadIdx.x;
    if (idx < 7200) {
        int d  = idx % 100;
        int tt = (idx / 100) % 4;
        int dg = idx / 400;
        const float* wih = wd_wih0 + dg * 144;
        float acc = 0.f;
        if (tt == 0) {        // offset -2
            for (int o = 0; o < 48; ++o) acc += wih[96 + o] * cw4[o * 400 + d * 4 + 0];
        } else if (tt == 1) { // offset -1
            for (int o = 0; o < 48; ++o) acc += wih[o]      * cw2[o * 200 + d * 2 + 0];
            for (int o = 0; o < 48; ++o) acc += wih[48 + o] * cw3[o * 300 + d * 3 + 0];
            for (int o = 0; o < 48; ++o) acc += wih[96 + o] * cw4[o * 400 + d * 4 + 1];
        } else if (tt == 2) { // offset 0
            for (int o = 0; o < 48; ++o) acc += wih[o]      * cw2[o * 200 + d * 2 + 1];
            for (int o = 0; o < 48; ++o) acc += wih[48 + o] * cw3[o * 300 + d * 3 + 1];
            for (int o = 0; o < 48; ++o) acc += wih[96 + o] * cw4[o * 400 + d * 4 + 2];
        } else {              // offset +1
            for (int o = 0; o < 48; ++o) acc += wih[48 + o] * cw3[o * 300 + d * 3 + 2];
            for (int o = 0; o < 48; ++o) acc += wih[96 + o] * cw4[o * 400 + d * 4 + 3];
        }
        E[idx] = acc;
    } else if (idx < 7218) {
        int dg = idx - 7200;
        float acc = wd_bih0[dg];
        for (int o = 0; o < 48; ++o) acc += wd_wih0[dg * 144 + o]      * cb2[o];
        for (int o = 0; o < 48; ++o) acc += wd_wih0[dg * 144 + 48 + o] * cb3[o];
        for (int o = 0; o < 48; ++o) acc += wd_wih0[dg * 144 + 96 + o] * cb4[o];
        if (is_rz(dg)) acc += wd_bhh0[dg];
        beff[dg] = gscale(dg) * acc;
    } else if (idx < 8244) {
        int k = idx - 7218;
        int dg = k % 18;
        int p  = k / 18;
        float acc = pos_bih0[dg];
        for (int d = 0; d < 100; ++d) acc += pos_emb[p * 100 + d] * pos_wih0[dg * 100 + d];
        if (is_rz(dg)) acc += pos_bhh0[dg];
        Gp[p * 18 + dg] = gscale(dg) * acc;
    } else if (idx < 8352) {
        int i = idx - 8244; int dg = i / 6;
        wih1t[i] = gscale(dg) * wd_wih1[i];
    } else if (idx < 8370) {
        int dg = idx - 8352;
        float a = wd_bih1[dg] + (is_rz(dg) ? wd_bhh1[dg] : 0.f);
        bih1t[dg] = gscale(dg) * a;
    } else if (idx < 8478) {
        int i = idx - 8370; int dg = i / 6;
        wih1t[108 + i] = gscale(dg) * pos_wih1[i];
    } else if (idx < 8496) {
        int dg = idx - 8478;
        float a = pos_bih1[dg] + (is_rz(dg) ? pos_bhh1[dg] : 0.f);
        bih1t[18 + dg] = gscale(dg) * a;
    }
}

// ---------------------------------------------------------------------------
// 2. P~[v][tap][dg] = s_g * (wd_emb[v,:] . E[dg][tap][:])  (R6, reg-blocked)
// ---------------------------------------------------------------------------
__global__ void __launch_bounds__(256) k_build_P(const float* __restrict__ wd_emb,
                                                 const float* __restrict__ E,
                                                 float* __restrict__ P)
{
    __shared__ float sEt[7200]; // [d][r], r = tt*18+dg
    for (int i = threadIdx.x; i < 7200; i += 256) {
        int d = i % 100, r = i / 100;
        int tt = r / 18, dg = r % 18;
        sEt[d * 72 + r] = E[dg * 400 + tt * 100 + d];
    }
    __syncthreads();
    int T = blockIdx.x * 256 + threadIdx.x;
    int og = T & 7;
    int vb = T >> 3;
    int v0 = vb * 4;
    if (v0 >= VV) return;
    int vlim = VV - 1 - v0;
    float gs[9];
#pragma unroll
    for (int k = 0; k < 9; ++k) {
        int dg = (og * 9 + k) % 18;
        gs[k] = ((dg % 9) / 3 == 2) ? TL2E : NL2E;
    }
    float acc[4][9];
#pragma unroll
    for (int vi = 0; vi < 4; ++vi)
#pragma unroll
        for (int k = 0; k < 9; ++k) acc[vi][k] = 0.f;

    const float* e0 = wd_emb + (size_t)v0 * 100;
#pragma unroll 1
    for (int d4 = 0; d4 < 25; ++d4) {
        float4 ev[4];
#pragma unroll
        for (int vi = 0; vi < 4; ++vi) {
            int vv = vi <= vlim ? vi : vlim;
            ev[vi] = *(const float4*)(e0 + vv * 100 + d4 * 4);
        }
#pragma unroll
        for (int dd = 0; dd < 4; ++dd) {
            int d = d4 * 4 + dd;
            const float* et = sEt + d * 72 + og * 9;
            float em0 = ((const float*)&ev[0])[dd];
            float em1 = ((const float*)&ev[1])[dd];
            float em2 = ((const float*)&ev[2])[dd];
            float em3 = ((const float*)&ev[3])[dd];
#pragma unroll
            for (int k = 0; k < 9; ++k) {
                float e = et[k];
                acc[0][k] = fmaf(em0, e, acc[0][k]);
                acc[1][k] = fmaf(em1, e, acc[1][k]);
                acc[2][k] = fmaf(em2, e, acc[2][k]);
                acc[3][k] = fmaf(em3, e, acc[3][k]);
            }
        }
    }
#pragma unroll
    for (int vi = 0; vi < 4; ++vi) {
        if (vi <= vlim) {
            float* p = P + (size_t)(v0 + vi) * 72 + og * 9;
#pragma unroll
            for (int k = 0; k < 9; ++k) p[k] = gs[k] * acc[vi][k];
        }
    }
}

// ---------------------------------------------------------------------------
// 3. Gather (R6): one thread per (branch,b,l), all 18 gates.
//    gx layout: [(branch*2+dir)*BB + b][l][j][g]
// ---------------------------------------------------------------------------
__global__ void k_gather(const int* __restrict__ wd, const int* __restrict__ pos,
                         const float* __restrict__ P, const float* __restrict__ beff,
                         const float* __restrict__ Gp, float* __restrict__ gx)
{
    int idx = blockIdx.x * blockDim.x + threadIdx.x;
    if (idx >= 2 * BB * LL) return;
    int branch = idx >= BB * LL;
    int k = idx - branch * BB * LL;
    int l = k % LL, b = k / LL;

    float v[18];
    if (!branch) {
#pragma unroll
        for (int i = 0; i < 18; ++i) v[i] = beff[i];
        const int* row = wd + b * LL;
#pragma unroll
        for (int t = 0; t < 4; ++t) {
            int ll = l - 2 + t;
            if (ll >= 0 && ll < LL) {
                const float* p = P + (long)row[ll] * 72 + t * 18;
#pragma unroll
                for (int i = 0; i < 18; ++i) v[i] += p[i];
            }
        }
    } else {
        const float* p = Gp + pos[k] * 18;
#pragma unroll
        for (int i = 0; i < 18; ++i) v[i] = p[i];
    }
    long base0 = ((long)(branch * 2 + 0) * BB + b) * (LL * 9) + l * 9;
    long base1 = ((long)(branch * 2 + 1) * BB + b) * (LL * 9) + l * 9;
#pragma unroll
    for (int j = 0; j < 3; ++j)
#pragma unroll
        for (int g = 0; g < 3; ++g) {
            gx[base0 + j * 3 + g] = v[g * 3 + j];
            gx[base1 + j * 3 + g] = v[9 + g * 3 + j];
        }
}

// ---------------------------------------------------------------------------
// 4. Scan layer 0 (reads gx linearly). 32 chunks/chain, 16 real + 48 warm.
//    2 blocks/chain; 4096 blocks. out layout: [chain][l][4].
// ---------------------------------------------------------------------------
__global__ void __launch_bounds__(64) k_scan0(
        const float* __restrict__ gx0, float* __restrict__ out,
        const float* __restrict__ whhA, const float* __restrict__ bhhA,
        const float* __restrict__ whhB, const float* __restrict__ bhhB)
{
    __shared__ float lbuf[8 * 81];
    int lane = threadIdx.x;
    int c = lane >> 2, sub = lane & 3;
    int jj = sub < 3 ? sub : 2;
    int chain = blockIdx.x >> 1;
    int ck = ((blockIdx.x & 1) << 4) + c;   // chunk 0..31
    int branch = chain >> 10;
    int rem = chain & 1023;
    int dir = rem >> 9;

    const float* whh = (branch ? whhB : whhA) + dir * 27;
    const float* bhh = (branch ? bhhB : bhhA) + dir * 9;

    float wr0 = NL2E * whh[jj * 3 + 0], wr1 = NL2E * whh[jj * 3 + 1], wr2 = NL2E * whh[jj * 3 + 2];
    float wz0 = NL2E * whh[(3 + jj) * 3 + 0], wz1 = NL2E * whh[(3 + jj) * 3 + 1], wz2 = NL2E * whh[(3 + jj) * 3 + 2];
    float wn0 = TL2E * whh[(6 + jj) * 3 + 0], wn1 = TL2E * whh[(6 + jj) * 3 + 1], wn2 = TL2E * whh[(6 + jj) * 3 + 2];
    float bnx = TL2E * bhh[6 + jj];

    int t0 = ck * 16 - 48;
    auto lof = [&](int t) { int tc = t < 0 ? 0 : (t > 511 ? 511 : t); return dir ? (511 - tc) : tc; };

    const char* gxc = (const char*)gx0 + (size_t)chain * (LL * 36) + jj * 12;
    F3 buf[8];
#pragma unroll
    for (int s = 0; s < 8; ++s)
        buf[s] = *(const F3*)(gxc + (size_t)lof(t0 + s) * 36);
    int pft = t0 + 8;

    char* ob = (char*)out + (size_t)chain * (LL * 16) + sub * 32;

    float h = 0.f;
    for (int g = 0; g < 8; ++g) {
#pragma unroll
        for (int s = 0; s < 8; ++s) {
            int t = t0 + g * 8 + s;
            F3 gv = buf[s];
            buf[s] = *(const F3*)(gxc + (size_t)lof(pft) * 36);
            ++pft;

            float h0 = qb<0>(h), h1 = qb<1>(h), h2 = qb<2>(h);
            float hm1 = h - 1.f;
            float sr = fmaf(wr0, h0, gv.r) + fmaf(wr1, h1, wr2 * h2);
            float sz = fmaf(wz0, h0, gv.z) + fmaf(wz1, h1, wz2 * h2);
            float gn3 = fmaf(wn0, h0, fmaf(wn1, h1, fmaf(wn2, h2, bnx)));
            float r = rcp_(1.f + exp2_(sr));
            float z = rcp_(1.f + exp2_(sz));
            float y2 = fmaf(r, gn3, gv.n);
            float u = rcp_(1.f + exp2_(y2));
            float a = fmaf(2.f, u, hm1);
            float n = fmaf(-2.f, u, 1.f);
            float hn = fmaf(z, a, n);
            h = (t >= 0) ? hn : 0.f;
            lbuf[s * 81 + c * 5 + sub] = h;
        }
        __syncthreads();
        if (g >= 6) {
            int tbase = t0 + g * 8;
            int l0 = dir ? (LL - 1 - tbase - 7) : tbase;
#pragma unroll
            for (int i = 0; i < 2; ++i) {
                int lofs = sub * 2 + i;
                int s = dir ? (7 - lofs) : lofs;
                float4 vv;
                vv.x = lbuf[s * 81 + c * 5 + 0];
                vv.y = lbuf[s * 81 + c * 5 + 1];
                vv.z = lbuf[s * 81 + c * 5 + 2];
                vv.w = lbuf[s * 81 + c * 5 + 3];
                *(float4*)(ob + (size_t)l0 * 16 + i * 16) = vv;
            }
        }
        __syncthreads();
    }
}

// ---------------------------------------------------------------------------
// 5. Scan layer 1 with fused input projection (R7, validated). 32 chunks,
//    16 real + 48 warm; 4096 blocks.
// ---------------------------------------------------------------------------
__global__ void __launch_bounds__(64) k_scan1(
        const float* __restrict__ out0, float* __restrict__ out1,
        const float* __restrict__ whhA, const float* __restrict__ bhhA,
        const float* __restrict__ whhB, const float* __restrict__ bhhB,
        const float* __restrict__ wih1t, const float* __restrict__ bih1t)
{
    __shared__ float lbuf[8 * 81];
    int lane = threadIdx.x;
    int c = lane >> 2, sub = lane & 3;
    int jj = sub < 3 ? sub : 2;
    int chain = blockIdx.x >> 1;
    int ck = ((blockIdx.x & 1) << 4) + c;   // chunk 0..31
    int branch = chain >> 10;
    int rem = chain & 1023;
    int dir = rem >> 9;
    int b = rem & 511;

    const float* whh = (branch ? whhB : whhA) + dir * 27;
    const float* bhh = (branch ? bhhB : bhhA) + dir * 9;

    float wr0 = NL2E * whh[jj * 3 + 0], wr1 = NL2E * whh[jj * 3 + 1], wr2 = NL2E * whh[jj * 3 + 2];
    float wz0 = NL2E * whh[(3 + jj) * 3 + 0], wz1 = NL2E * whh[(3 + jj) * 3 + 1], wz2 = NL2E * whh[(3 + jj) * 3 + 2];
    float wn0 = TL2E * whh[(6 + jj) * 3 + 0], wn1 = TL2E * whh[(6 + jj) * 3 + 1], wn2 = TL2E * whh[(6 + jj) * 3 + 2];
    float bnx = TL2E * bhh[6 + jj];

    const float* Wb = wih1t + branch * 108;
    const float* Bv = bih1t + branch * 18;
    int dgr = dir * 9 + jj, dgz = dgr + 3, dgn = dgr + 6;
    float Wr[6], Wz[6], Wn[6];
#pragma unroll
    for (int q = 0; q < 6; ++q) {
        Wr[q] = Wb[dgr * 6 + q];
        Wz[q] = Wb[dgz * 6 + q];
        Wn[q] = Wb[dgn * 6 + q];
    }
    float Br = Bv[dgr], Bz = Bv[dgz], Bn = Bv[dgn];

    const float4* o0 = (const float4*)out0 + (size_t)((branch * 2 + 0) * BB + b) * LL;
    const float4* o1 = (const float4*)out0 + (size_t)((branch * 2 + 1) * BB + b) * LL;

    int t0 = ck * 16 - 48;
    auto lof = [&](int t) { int tc = t < 0 ? 0 : (t > 511 ? 511 : t); return dir ? (511 - tc) : tc; };

    float4 bf[8], bg[8];
#pragma unroll
    for (int s = 0; s < 8; ++s) {
        int l = lof(t0 + s);
        bf[s] = o0[l]; bg[s] = o1[l];
    }
    int pft = t0 + 8;

    char* ob = (char*)out1 + (size_t)chain * (LL * 16) + sub * 32;

    float h = 0.f;
    for (int g = 0; g < 8; ++g) {
#pragma unroll
        for (int s = 0; s < 8; ++s) {
            int t = t0 + g * 8 + s;
            float4 f4 = bf[s], q4 = bg[s];
            int lpf = lof(pft);
            bf[s] = o0[lpf]; bg[s] = o1[lpf];
            ++pft;

            float gr = Br, gz = Bz, gn = Bn;
            gr = fmaf(f4.x, Wr[0], gr); gr = fmaf(f4.y, Wr[1], gr); gr = fmaf(f4.z, Wr[2], gr);
            gr = fmaf(q4.x, Wr[3], gr); gr = fmaf(q4.y, Wr[4], gr); gr = fmaf(q4.z, Wr[5], gr);
            gz = fmaf(f4.x, Wz[0], gz); gz = fmaf(f4.y, Wz[1], gz); gz = fmaf(f4.z, Wz[2], gz);
            gz = fmaf(q4.x, Wz[3], gz); gz = fmaf(q4.y, Wz[4], gz); gz = fmaf(q4.z, Wz[5], gz);
            gn = fmaf(f4.x, Wn[0], gn); gn = fmaf(f4.y, Wn[1], gn); gn = fmaf(f4.z, Wn[2], gn);
            gn = fmaf(q4.x, Wn[3], gn); gn = fmaf(q4.y, Wn[4], gn); gn = fmaf(q4.z, Wn[5], gn);

            float h0 = qb<0>(h), h1 = qb<1>(h), h2 = qb<2>(h);
            float hm1 = h - 1.f;
            float sr = fmaf(wr0, h0, gr) + fmaf(wr1, h1, wr2 * h2);
            float sz = fmaf(wz0, h0, gz) + fmaf(wz1, h1, wz2 * h2);
            float gn3 = fmaf(wn0, h0, fmaf(wn1, h1, fmaf(wn2, h2, bnx)));
            float r = rcp_(1.f + exp2_(sr));
            float z = rcp_(1.f + exp2_(sz));
            float y2 = fmaf(r, gn3, gn);
            float u = rcp_(1.f + exp2_(y2));
            float a = fmaf(2.f, u, hm1);
            float n = fmaf(-2.f, u, 1.f);
            float hn = fmaf(z, a, n);
            h = (t >= 0) ? hn : 0.f;
            lbuf[s * 81 + c * 5 + sub] = h;
        }
        __syncthreads();
        if (g >= 6) {
            int tbase = t0 + g * 8;
            int l0 = dir ? (LL - 1 - tbase - 7) : tbase;
#pragma unroll
            for (int i = 0; i < 2; ++i) {
                int lofs = sub * 2 + i;
                int s = dir ? (7 - lofs) : lofs;
                float4 vv;
                vv.x = lbuf[s * 81 + c * 5 + 0];
                vv.y = lbuf[s * 81 + c * 5 + 1];
                vv.z = lbuf[s * 81 + c * 5 + 2];
                vv.w = lbuf[s * 81 + c * 5 + 3];
                *(float4*)(ob + (size_t)l0 * 16 + i * 16) = vv;
            }
        }
        __syncthreads();
    }
}

// ---------------------------------------------------------------------------
// 6. Fused head: attention over wd_out + posfc/auxi + fc1/fc2 softmax.
// ---------------------------------------------------------------------------
__global__ void k_head(const float* __restrict__ out1,
                       const float* __restrict__ sw, const float* __restrict__ ap,
                       const float* __restrict__ pg, const float* __restrict__ pb,
                       const float* __restrict__ pw, const float* __restrict__ pbias,
                       const float* __restrict__ f1w, const float* __restrict__ f1b,
                       const float* __restrict__ fg, const float* __restrict__ fb,
                       const float* __restrict__ f2w, const float* __restrict__ f2b,
                       float* __restrict__ out)
{
    int b = blockIdx.x;
    int lane = threadIdx.x;
    __shared__ float ssw[36], sap[6], sph[6], scomb[9], sh[128], sl[6], se[6];
    const float BN = 0.9999950000374997f; // 1/sqrt(1+1e-5)

    if (lane < 36) ssw[lane] = sw[lane];
    if (lane < 6) {
        sap[lane] = ap[lane];
        const float* posf = out1 + (size_t)((2 * BB) + b) * LL * 4 + 511 * 4;
        const float* posb = out1 + (size_t)((3 * BB) + b) * LL * 4 + 511 * 4;
        float v = lane < 3 ? posf[lane] : posb[lane - 3];
        float x = v * BN * pg[lane] + pb[lane];
        sph[lane] = fmaxf(x, 0.f);
    }
    __syncthreads();

    const float* F = out1 + (size_t)b * LL * 4;
    const float* Bw = out1 + (size_t)(BB + b) * LL * 4;

    float att[8];
    float mx = -1e30f;
#pragma unroll
    for (int k = 0; k < 8; ++k) {
        int l = lane + 64 * k;
        float4 f4 = *(const float4*)(F + l * 4);
        float4 b4 = *(const float4*)(Bw + l * 4);
        float r0 = f4.x, r1 = f4.y, r2 = f4.z, r3 = b4.x, r4 = b4.y, r5 = b4.z;
        float a = 0.f;
#pragma unroll
        for (int j = 0; j < 6; ++j) {
            float s = r0 * ssw[0 * 6 + j] + r1 * ssw[1 * 6 + j] + r2 * ssw[2 * 6 + j] +
                      r3 * ssw[3 * 6 + j] + r4 * ssw[4 * 6 + j] + r5 * ssw[5 * 6 + j];
            a += sap[j] * tanh_(s);
        }
        att[k] = a;
        mx = fmaxf(mx, a);
    }
#pragma unroll
    for (int off = 32; off; off >>= 1) mx = fmaxf(mx, __shfl_xor(mx, off));
    float e[8];
    float sum = 0.f;
#pragma unroll
    for (int k = 0; k < 8; ++k) { e[k] = exp2_(L2E * (att[k] - mx)); sum += e[k]; }
#pragma unroll
    for (int off = 32; off; off >>= 1) sum += __shfl_xor(sum, off);

    float acc[6] = {0.f, 0.f, 0.f, 0.f, 0.f, 0.f};
#pragma unroll
    for (int k = 0; k < 8; ++k) {
        int l = lane + 64 * k;
        float4 f4 = *(const float4*)(F + l * 4);
        float4 b4 = *(const float4*)(Bw + l * 4);
        acc[0] += e[k] * f4.x; acc[1] += e[k] * f4.y; acc[2] += e[k] * f4.z;
        acc[3] += e[k] * b4.x; acc[4] += e[k] * b4.y; acc[5] += e[k] * b4.z;
    }
#pragma unroll
    for (int j = 0; j < 6; ++j) {
#pragma unroll
        for (int off = 32; off; off >>= 1) acc[j] += __shfl_xor(acc[j], off);
    }
    if (lane < 6) scomb[lane] = acc[lane] / sum;
    __syncthreads();

    if (lane == 0) {
        float a[3];
#pragma unroll
        for (int j = 0; j < 3; ++j) {
            float t = pbias[j];
#pragma unroll
            for (int i = 0; i < 6; ++i) t += sph[i] * pw[j * 6 + i];
            a[j] = t;
        }
        float m = fmaxf(a[0], fmaxf(a[1], a[2]));
        float e0 = exp2_(L2E * (a[0] - m)), e1 = exp2_(L2E * (a[1] - m)), e2 = exp2_(L2E * (a[2] - m));
        float s = e0 + e1 + e2;
        float x0 = e0 / s, x1 = e1 / s, x2 = e2 / s;
        scomb[6] = x0; scomb[7] = x1; scomb[8] = x2;
        out[BB * 6 + b * 3 + 0] = x0;
        out[BB * 6 + b * 3 + 1] = x1;
        out[BB * 6 + b * 3 + 2] = x2;
    }
    __syncthreads();
    for (int o = lane; o < 128; o += 64) {
        float t = f1b[o];
#pragma unroll
        for (int k = 0; k < 9; ++k) t += scomb[k] * f1w[o * 9 + k];
        float x = t * BN * fg[o] + fb[o];
        sh[o] = fmaxf(x, 0.f);
    }
    __syncthreads();
    if (lane < 6) {
        float t = f2b[lane];
        for (int k = 0; k < 128; ++k) t += sh[k] * f2w[lane * 128 + k];
        sl[lane] = t;
    }
    __syncthreads();
    if (lane < 6) {
        float m = sl[0];
#pragma unroll
        for (int j = 1; j < 6; ++j) m = fmaxf(m, sl[j]);
        se[lane] = exp2_(L2E * (sl[lane] - m));
    }
    __syncthreads();
    if (lane < 6) {
        float s = se[0] + se[1] + se[2] + se[3] + se[4] + se[5];
        out[b * 6 + lane] = se[lane] / s;
    }
}

// ---------------------------------------------------------------------------
extern "C" void kernel_launch(void* const* d_in, const int* in_sizes, int n_in,
                              void* d_out, int out_size, void* d_ws, size_t ws_size,
                              hipStream_t stream)
{
    const int* wd  = (const int*)d_in[0];
    const int* pos = (const int*)d_in[1];
    const float* wd_emb  = (const float*)d_in[2];
    const float* pos_emb = (const float*)d_in[3];
    const float* cw2 = (const float*)d_in[4];  const float* cb2 = (const float*)d_in[5];
    const float* cw3 = (const float*)d_in[6];  const float* cb3 = (const float*)d_in[7];
    const float* cw4 = (const float*)d_in[8];  const float* cb4 = (const float*)d_in[9];
    const float* wd_wih0 = (const float*)d_in[10]; const float* wd_whh0 = (const float*)d_in[11];
    const float* wd_bih0 = (const float*)d_in[12]; const float* wd_bhh0 = (const float*)d_in[13];
    const float* wd_wih1 = (const float*)d_in[14]; const float* wd_whh1 = (const float*)d_in[15];
    const float* wd_bih1 = (const float*)d_in[16]; const float* wd_bhh1 = (const float*)d_in[17];
    const float* pos_wih0 = (const float*)d_in[18]; const float* pos_whh0 = (const float*)d_in[19];
    const float* pos_bih0 = (const float*)d_in[20]; const float* pos_bhh0 = (const float*)d_in[21];
    const float* pos_wih1 = (const float*)d_in[22]; const float* pos_whh1 = (const float*)d_in[23];
    const float* pos_bih1 = (const float*)d_in[24]; const float* pos_bhh1 = (const float*)d_in[25];
    const float* squish_w   = (const float*)d_in[26];
    const float* atten_proj = (const float*)d_in[27];
    const float* posfc_gamma = (const float*)d_in[28]; const float* posfc_beta = (const float*)d_in[29];
    const float* posfc_w = (const float*)d_in[30]; const float* posfc_b = (const float*)d_in[31];
    const float* fc1_w = (const float*)d_in[32]; const float* fc1_b = (const float*)d_in[33];
    const float* fc_gamma = (const float*)d_in[34]; const float* fc_beta = (const float*)d_in[35];
    const float* fc2_w = (const float*)d_in[36]; const float* fc2_b = (const float*)d_in[37];

    float* ws = (float*)d_ws;
    size_t off = 0;
    float* P = ws + off;      off += (size_t)VV * 72 + 8;
    float* gx = ws + off;     off += (size_t)4 * BB * LL * 9;
    float* out0 = ws + off;   off += (size_t)4 * BB * LL * 4;
    float* out1 = ws + off;   off += (size_t)4 * BB * LL * 4;
    float* Etab = ws + off;   off += 7200;
    float* beff = ws + off;   off += 32;
    float* Gp = ws + off;     off += PP * 18 + 14;
    float* wih1t = ws + off;  off += 216;
    float* bih1t = ws + off;  off += 40;

    k_build_tables<<<(8496 + 255) / 256, 256, 0, stream>>>(
        wd_wih0, wd_bih0, wd_bhh0, cw2, cb2, cw3, cb3, cw4, cb4,
        pos_emb, pos_wih0, pos_bih0, pos_bhh0,
        wd_wih1, wd_bih1, wd_bhh1, pos_wih1, pos_bih1, pos_bhh1,
        Etab, beff, Gp, wih1t, bih1t);
    {
        int vb = (VV + 3) / 4;
        int threads = vb * 8;
        k_build_P<<<(threads + 255) / 256, 256, 0, stream>>>(wd_emb, Etab, P);
    }
    k_gather<<<(2 * BB * LL + 255) / 256, 256, 0, stream>>>(wd, pos, P, beff, Gp, gx);
    k_scan0<<<4096, 64, 0, stream>>>(gx, out0, wd_whh0, wd_bhh0, pos_whh0, pos_bhh0);
    k_scan1<<<4096, 64, 0, stream>>>(out0, out1, wd_whh1, wd_bhh1, pos_whh1, pos_bhh1,
                                     wih1t, bih1t);
    k_head<<<BB, 64, 0, stream>>>(out1, squish_w, atten_proj, posfc_gamma, posfc_beta,
                                  posfc_w, posfc_b, fc1_w, fc1_b, fc_gamma, fc_beta,
                                  fc2_w, fc2_b, (float*)d_out);
}

// Round 9
// 118.927 us; speedup vs baseline: 1.3308x; 1.1604x over previous
//
#include <hip/hip_runtime.h>
#include <math.h>

#define BB 512   // batch
#define LL 512   // seq len
#define VV 23757 // wd vocab
#define PP 57    // pos vocab

#define L2E  1.4426950408889634f
#define NL2E (-1.4426950408889634f)
#define TL2E 2.8853900817779268f   // 2*log2(e)

__device__ __forceinline__ float rcp_(float x) { return __builtin_amdgcn_rcpf(x); }
__device__ __forceinline__ float exp2_(float x) { return __builtin_amdgcn_exp2f(x); }
__device__ __forceinline__ float tanh_(float x) { return 1.f - 2.f * rcp_(exp2_(TL2E * x) + 1.f); }

// gate scale: r,z -> -log2e ; n -> 2*log2e   (dg = dir*9 + g*3 + j)
__device__ __forceinline__ float gscale(int dg) {
    int g = (dg % 9) / 3;
    return g == 2 ? TL2E : NL2E;
}
__device__ __forceinline__ int is_rz(int dg) { return ((dg % 9) / 3) < 2; }

// quad_perm broadcast of lane K (0..2) within each 4-lane group, via DPP.
template <int K>
__device__ __forceinline__ float qb(float x) {
    constexpr int ctrl = K * 0x55;
    return __int_as_float(__builtin_amdgcn_update_dpp(0, __float_as_int(x), ctrl, 0xF, 0xF, true));
}

struct F3 { float r, z, n; };

// ---------------------------------------------------------------------------
// 1. Tables (prescaled for exp2-form gates), gate-major layouts.
// ---------------------------------------------------------------------------
__global__ void k_build_tables(const float* __restrict__ wd_wih0, const float* __restrict__ wd_bih0,
                               const float* __restrict__ wd_bhh0,
                               const float* __restrict__ cw2, const float* __restrict__ cb2,
                               const float* __restrict__ cw3, const float* __restrict__ cb3,
                               const float* __restrict__ cw4, const float* __restrict__ cb4,
                               const float* __restrict__ pos_emb,
                               const float* __restrict__ pos_wih0, const float* __restrict__ pos_bih0,
                               const float* __restrict__ pos_bhh0,
                               const float* __restrict__ wd_wih1, const float* __restrict__ wd_bih1,
                               const float* __restrict__ wd_bhh1,
                               const float* __restrict__ pos_wih1, const float* __restrict__ pos_bih1,
                               const float* __restrict__ pos_bhh1,
                               float* __restrict__ E, float* __restrict__ beff, float* __restrict__ Gp,
                               float* __restrict__ wih1t, float* __restrict__ bih1t)
{
    int idx = blockIdx.x * blockDim.x + threadIdx.x;
    if (idx < 7200) {
        int d  = idx % 100;
        int tt = (idx / 100) % 4;
        int dg = idx / 400;
        const float* wih = wd_wih0 + dg * 144;
        float acc = 0.f;
        if (tt == 0) {        // offset -2
            for (int o = 0; o < 48; ++o) acc += wih[96 + o] * cw4[o * 400 + d * 4 + 0];
        } else if (tt == 1) { // offset -1
            for (int o = 0; o < 48; ++o) acc += wih[o]      * cw2[o * 200 + d * 2 + 0];
            for (int o = 0; o < 48; ++o) acc += wih[48 + o] * cw3[o * 300 + d * 3 + 0];
            for (int o = 0; o < 48; ++o) acc += wih[96 + o] * cw4[o * 400 + d * 4 + 1];
        } else if (tt == 2) { // offset 0
            for (int o = 0; o < 48; ++o) acc += wih[o]      * cw2[o * 200 + d * 2 + 1];
            for (int o = 0; o < 48; ++o) acc += wih[48 + o] * cw3[o * 300 + d * 3 + 1];
            for (int o = 0; o < 48; ++o) acc += wih[96 + o] * cw4[o * 400 + d * 4 + 2];
        } else {              // offset +1
            for (int o = 0; o < 48; ++o) acc += wih[48 + o] * cw3[o * 300 + d * 3 + 2];
            for (int o = 0; o < 48; ++o) acc += wih[96 + o] * cw4[o * 400 + d * 4 + 3];
        }
        E[idx] = acc;
    } else if (idx < 7218) {
        int dg = idx - 7200;
        float acc = wd_bih0[dg];
        for (int o = 0; o < 48; ++o) acc += wd_wih0[dg * 144 + o]      * cb2[o];
        for (int o = 0; o < 48; ++o) acc += wd_wih0[dg * 144 + 48 + o] * cb3[o];
        for (int o = 0; o < 48; ++o) acc += wd_wih0[dg * 144 + 96 + o] * cb4[o];
        if (is_rz(dg)) acc += wd_bhh0[dg];
        beff[dg] = gscale(dg) * acc;
    } else if (idx < 8244) {
        int k = idx - 7218;
        int dg = k % 18;
        int p  = k / 18;
        float acc = pos_bih0[dg];
        for (int d = 0; d < 100; ++d) acc += pos_emb[p * 100 + d] * pos_wih0[dg * 100 + d];
        if (is_rz(dg)) acc += pos_bhh0[dg];
        Gp[p * 18 + dg] = gscale(dg) * acc;
    } else if (idx < 8352) {
        int i = idx - 8244; int dg = i / 6;
        wih1t[i] = gscale(dg) * wd_wih1[i];
    } else if (idx < 8370) {
        int dg = idx - 8352;
        float a = wd_bih1[dg] + (is_rz(dg) ? wd_bhh1[dg] : 0.f);
        bih1t[dg] = gscale(dg) * a;
    } else if (idx < 8478) {
        int i = idx - 8370; int dg = i / 6;
        wih1t[108 + i] = gscale(dg) * pos_wih1[i];
    } else if (idx < 8496) {
        int dg = idx - 8478;
        float a = pos_bih1[dg] + (is_rz(dg) ? pos_bhh1[dg] : 0.f);
        bih1t[18 + dg] = gscale(dg) * a;
    }
}

// ---------------------------------------------------------------------------
// 2. P~[v][tap][dg] = s_g * (wd_emb[v,:] . E[dg][tap][:])  (reg-blocked)
// ---------------------------------------------------------------------------
__global__ void __launch_bounds__(256) k_build_P(const float* __restrict__ wd_emb,
                                                 const float* __restrict__ E,
                                                 float* __restrict__ P)
{
    __shared__ float sEt[7200]; // [d][r], r = tt*18+dg
    for (int i = threadIdx.x; i < 7200; i += 256) {
        int d = i % 100, r = i / 100;
        int tt = r / 18, dg = r % 18;
        sEt[d * 72 + r] = E[dg * 400 + tt * 100 + d];
    }
    __syncthreads();
    int T = blockIdx.x * 256 + threadIdx.x;
    int og = T & 7;
    int vb = T >> 3;
    int v0 = vb * 4;
    if (v0 >= VV) return;
    int vlim = VV - 1 - v0;
    float gs[9];
#pragma unroll
    for (int k = 0; k < 9; ++k) {
        int dg = (og * 9 + k) % 18;
        gs[k] = ((dg % 9) / 3 == 2) ? TL2E : NL2E;
    }
    float acc[4][9];
#pragma unroll
    for (int vi = 0; vi < 4; ++vi)
#pragma unroll
        for (int k = 0; k < 9; ++k) acc[vi][k] = 0.f;

    const float* e0 = wd_emb + (size_t)v0 * 100;
#pragma unroll 1
    for (int d4 = 0; d4 < 25; ++d4) {
        float4 ev[4];
#pragma unroll
        for (int vi = 0; vi < 4; ++vi) {
            int vv = vi <= vlim ? vi : vlim;
            ev[vi] = *(const float4*)(e0 + vv * 100 + d4 * 4);
        }
#pragma unroll
        for (int dd = 0; dd < 4; ++dd) {
            int d = d4 * 4 + dd;
            const float* et = sEt + d * 72 + og * 9;
            float em0 = ((const float*)&ev[0])[dd];
            float em1 = ((const float*)&ev[1])[dd];
            float em2 = ((const float*)&ev[2])[dd];
            float em3 = ((const float*)&ev[3])[dd];
#pragma unroll
            for (int k = 0; k < 9; ++k) {
                float e = et[k];
                acc[0][k] = fmaf(em0, e, acc[0][k]);
                acc[1][k] = fmaf(em1, e, acc[1][k]);
                acc[2][k] = fmaf(em2, e, acc[2][k]);
                acc[3][k] = fmaf(em3, e, acc[3][k]);
            }
        }
    }
#pragma unroll
    for (int vi = 0; vi < 4; ++vi) {
        if (vi <= vlim) {
            float* p = P + (size_t)(v0 + vi) * 72 + og * 9;
#pragma unroll
            for (int k = 0; k < 9; ++k) p[k] = gs[k] * acc[vi][k];
        }
    }
}

// ---------------------------------------------------------------------------
// 3. Gather: one thread per (branch,b,l), all 18 gates.
//    gx layout: [(branch*2+dir)*BB + b][l][j][g]
// ---------------------------------------------------------------------------
__global__ void k_gather(const int* __restrict__ wd, const int* __restrict__ pos,
                         const float* __restrict__ P, const float* __restrict__ beff,
                         const float* __restrict__ Gp, float* __restrict__ gx)
{
    int idx = blockIdx.x * blockDim.x + threadIdx.x;
    if (idx >= 2 * BB * LL) return;
    int branch = idx >= BB * LL;
    int k = idx - branch * BB * LL;
    int l = k % LL, b = k / LL;

    float v[18];
    if (!branch) {
#pragma unroll
        for (int i = 0; i < 18; ++i) v[i] = beff[i];
        const int* row = wd + b * LL;
#pragma unroll
        for (int t = 0; t < 4; ++t) {
            int ll = l - 2 + t;
            if (ll >= 0 && ll < LL) {
                const float* p = P + (long)row[ll] * 72 + t * 18;
#pragma unroll
                for (int i = 0; i < 18; ++i) v[i] += p[i];
            }
        }
    } else {
        const float* p = Gp + pos[k] * 18;
#pragma unroll
        for (int i = 0; i < 18; ++i) v[i] = p[i];
    }
    long base0 = ((long)(branch * 2 + 0) * BB + b) * (LL * 9) + l * 9;
    long base1 = ((long)(branch * 2 + 1) * BB + b) * (LL * 9) + l * 9;
#pragma unroll
    for (int j = 0; j < 3; ++j)
#pragma unroll
        for (int g = 0; g < 3; ++g) {
            gx[base0 + j * 3 + g] = v[g * 3 + j];
            gx[base1 + j * 3 + g] = v[9 + g * 3 + j];
        }
}

// ---------------------------------------------------------------------------
// 4. Scan layer 0. R=32 real/chunk, W=48 warm -> 80 steps (10 groups of 8).
//    16 chunks/block, 2048 blocks. out layout: [chain][l][4].
// ---------------------------------------------------------------------------
__global__ void __launch_bounds__(64) k_scan0(
        const float* __restrict__ gx0, float* __restrict__ out,
        const float* __restrict__ whhA, const float* __restrict__ bhhA,
        const float* __restrict__ whhB, const float* __restrict__ bhhB)
{
    __shared__ float lbuf[8 * 81];
    int lane = threadIdx.x;
    int c = lane >> 2, sub = lane & 3;   // c = chunk 0..15
    int jj = sub < 3 ? sub : 2;
    int chain = blockIdx.x;
    int branch = chain >> 10;
    int rem = chain & 1023;
    int dir = rem >> 9;

    const float* whh = (branch ? whhB : whhA) + dir * 27;
    const float* bhh = (branch ? bhhB : bhhA) + dir * 9;

    float wr0 = NL2E * whh[jj * 3 + 0], wr1 = NL2E * whh[jj * 3 + 1], wr2 = NL2E * whh[jj * 3 + 2];
    float wz0 = NL2E * whh[(3 + jj) * 3 + 0], wz1 = NL2E * whh[(3 + jj) * 3 + 1], wz2 = NL2E * whh[(3 + jj) * 3 + 2];
    float wn0 = TL2E * whh[(6 + jj) * 3 + 0], wn1 = TL2E * whh[(6 + jj) * 3 + 1], wn2 = TL2E * whh[(6 + jj) * 3 + 2];
    float bnx = TL2E * bhh[6 + jj];

    int t0 = c * 32 - 48;
    auto lof = [&](int t) { int tc = t < 0 ? 0 : (t > 511 ? 511 : t); return dir ? (511 - tc) : tc; };

    const char* gxc = (const char*)gx0 + (size_t)chain * (LL * 36) + jj * 12;
    F3 buf[8];
#pragma unroll
    for (int s = 0; s < 8; ++s)
        buf[s] = *(const F3*)(gxc + (size_t)lof(t0 + s) * 36);
    int pft = t0 + 8;

    char* ob = (char*)out + (size_t)chain * (LL * 16) + sub * 32;

    float h = 0.f;
    for (int g = 0; g < 10; ++g) {
#pragma unroll
        for (int s = 0; s < 8; ++s) {
            int t = t0 + g * 8 + s;
            F3 gv = buf[s];
            buf[s] = *(const F3*)(gxc + (size_t)lof(pft) * 36);
            ++pft;

            float h0 = qb<0>(h), h1 = qb<1>(h), h2 = qb<2>(h);
            float hm1 = h - 1.f;
            float sr = fmaf(wr0, h0, gv.r) + fmaf(wr1, h1, wr2 * h2);
            float sz = fmaf(wz0, h0, gv.z) + fmaf(wz1, h1, wz2 * h2);
            float gn3 = fmaf(wn0, h0, fmaf(wn1, h1, fmaf(wn2, h2, bnx)));
            float r = rcp_(1.f + exp2_(sr));
            float z = rcp_(1.f + exp2_(sz));
            float y2 = fmaf(r, gn3, gv.n);
            float u = rcp_(1.f + exp2_(y2));
            float a = fmaf(2.f, u, hm1);
            float n = fmaf(-2.f, u, 1.f);
            float hn = fmaf(z, a, n);
            h = (t >= 0) ? hn : 0.f;
            lbuf[s * 81 + c * 5 + sub] = h;
        }
        __syncthreads();
        if (g >= 6) {
            int tbase = t0 + g * 8;
            int l0 = dir ? (LL - 1 - tbase - 7) : tbase;
#pragma unroll
            for (int i = 0; i < 2; ++i) {
                int lofs = sub * 2 + i;
                int s = dir ? (7 - lofs) : lofs;
                float4 vv;
                vv.x = lbuf[s * 81 + c * 5 + 0];
                vv.y = lbuf[s * 81 + c * 5 + 1];
                vv.z = lbuf[s * 81 + c * 5 + 2];
                vv.w = lbuf[s * 81 + c * 5 + 3];
                *(float4*)(ob + (size_t)l0 * 16 + i * 16) = vv;
            }
        }
        __syncthreads();
    }
}

// ---------------------------------------------------------------------------
// 5. Scan layer 1 with fused input projection. R=32, W=48, 2048 blocks.
// ---------------------------------------------------------------------------
__global__ void __launch_bounds__(64) k_scan1(
        const float* __restrict__ out0, float* __restrict__ out1,
        const float* __restrict__ whhA, const float* __restrict__ bhhA,
        const float* __restrict__ whhB, const float* __restrict__ bhhB,
        const float* __restrict__ wih1t, const float* __restrict__ bih1t)
{
    __shared__ float lbuf[8 * 81];
    int lane = threadIdx.x;
    int c = lane >> 2, sub = lane & 3;
    int jj = sub < 3 ? sub : 2;
    int chain = blockIdx.x;
    int branch = chain >> 10;
    int rem = chain & 1023;
    int dir = rem >> 9;
    int b = rem & 511;

    const float* whh = (branch ? whhB : whhA) + dir * 27;
    const float* bhh = (branch ? bhhB : bhhA) + dir * 9;

    float wr0 = NL2E * whh[jj * 3 + 0], wr1 = NL2E * whh[jj * 3 + 1], wr2 = NL2E * whh[jj * 3 + 2];
    float wz0 = NL2E * whh[(3 + jj) * 3 + 0], wz1 = NL2E * whh[(3 + jj) * 3 + 1], wz2 = NL2E * whh[(3 + jj) * 3 + 2];
    float wn0 = TL2E * whh[(6 + jj) * 3 + 0], wn1 = TL2E * whh[(6 + jj) * 3 + 1], wn2 = TL2E * whh[(6 + jj) * 3 + 2];
    float bnx = TL2E * bhh[6 + jj];

    const float* Wb = wih1t + branch * 108;
    const float* Bv = bih1t + branch * 18;
    int dgr = dir * 9 + jj, dgz = dgr + 3, dgn = dgr + 6;
    float Wr[6], Wz[6], Wn[6];
#pragma unroll
    for (int q = 0; q < 6; ++q) {
        Wr[q] = Wb[dgr * 6 + q];
        Wz[q] = Wb[dgz * 6 + q];
        Wn[q] = Wb[dgn * 6 + q];
    }
    float Br = Bv[dgr], Bz = Bv[dgz], Bn = Bv[dgn];

    const float4* o0 = (const float4*)out0 + (size_t)((branch * 2 + 0) * BB + b) * LL;
    const float4* o1 = (const float4*)out0 + (size_t)((branch * 2 + 1) * BB + b) * LL;

    int t0 = c * 32 - 48;
    auto lof = [&](int t) { int tc = t < 0 ? 0 : (t > 511 ? 511 : t); return dir ? (511 - tc) : tc; };

    float4 bf[8], bg[8];
#pragma unroll
    for (int s = 0; s < 8; ++s) {
        int l = lof(t0 + s);
        bf[s] = o0[l]; bg[s] = o1[l];
    }
    int pft = t0 + 8;

    char* ob = (char*)out1 + (size_t)chain * (LL * 16) + sub * 32;

    float h = 0.f;
    for (int g = 0; g < 10; ++g) {
#pragma unroll
        for (int s = 0; s < 8; ++s) {
            int t = t0 + g * 8 + s;
            float4 f4 = bf[s], q4 = bg[s];
            int lpf = lof(pft);
            bf[s] = o0[lpf]; bg[s] = o1[lpf];
            ++pft;

            float gr = Br, gz = Bz, gn = Bn;
            gr = fmaf(f4.x, Wr[0], gr); gr = fmaf(f4.y, Wr[1], gr); gr = fmaf(f4.z, Wr[2], gr);
            gr = fmaf(q4.x, Wr[3], gr); gr = fmaf(q4.y, Wr[4], gr); gr = fmaf(q4.z, Wr[5], gr);
            gz = fmaf(f4.x, Wz[0], gz); gz = fmaf(f4.y, Wz[1], gz); gz = fmaf(f4.z, Wz[2], gz);
            gz = fmaf(q4.x, Wz[3], gz); gz = fmaf(q4.y, Wz[4], gz); gz = fmaf(q4.z, Wz[5], gz);
            gn = fmaf(f4.x, Wn[0], gn); gn = fmaf(f4.y, Wn[1], gn); gn = fmaf(f4.z, Wn[2], gn);
            gn = fmaf(q4.x, Wn[3], gn); gn = fmaf(q4.y, Wn[4], gn); gn = fmaf(q4.z, Wn[5], gn);

            float h0 = qb<0>(h), h1 = qb<1>(h), h2 = qb<2>(h);
            float hm1 = h - 1.f;
            float sr = fmaf(wr0, h0, gr) + fmaf(wr1, h1, wr2 * h2);
            float sz = fmaf(wz0, h0, gz) + fmaf(wz1, h1, wz2 * h2);
            float gn3 = fmaf(wn0, h0, fmaf(wn1, h1, fmaf(wn2, h2, bnx)));
            float r = rcp_(1.f + exp2_(sr));
            float z = rcp_(1.f + exp2_(sz));
            float y2 = fmaf(r, gn3, gn);
            float u = rcp_(1.f + exp2_(y2));
            float a = fmaf(2.f, u, hm1);
            float n = fmaf(-2.f, u, 1.f);
            float hn = fmaf(z, a, n);
            h = (t >= 0) ? hn : 0.f;
            lbuf[s * 81 + c * 5 + sub] = h;
        }
        __syncthreads();
        if (g >= 6) {
            int tbase = t0 + g * 8;
            int l0 = dir ? (LL - 1 - tbase - 7) : tbase;
#pragma unroll
            for (int i = 0; i < 2; ++i) {
                int lofs = sub * 2 + i;
                int s = dir ? (7 - lofs) : lofs;
                float4 vv;
                vv.x = lbuf[s * 81 + c * 5 + 0];
                vv.y = lbuf[s * 81 + c * 5 + 1];
                vv.z = lbuf[s * 81 + c * 5 + 2];
                vv.w = lbuf[s * 81 + c * 5 + 3];
                *(float4*)(ob + (size_t)l0 * 16 + i * 16) = vv;
            }
        }
        __syncthreads();
    }
}

// ---------------------------------------------------------------------------
// 6. Fused head: attention over wd_out + posfc/auxi + fc1/fc2 softmax.
// ---------------------------------------------------------------------------
__global__ void k_head(const float* __restrict__ out1,
                       const float* __restrict__ sw, const float* __restrict__ ap,
                       const float* __restrict__ pg, const float* __restrict__ pb,
                       const float* __restrict__ pw, const float* __restrict__ pbias,
                       const float* __restrict__ f1w, const float* __restrict__ f1b,
                       const float* __restrict__ fg, const float* __restrict__ fb,
                       const float* __restrict__ f2w, const float* __restrict__ f2b,
                       float* __restrict__ out)
{
    int b = blockIdx.x;
    int lane = threadIdx.x;
    __shared__ float ssw[36], sap[6], sph[6], scomb[9], sh[128], sl[6], se[6];
    const float BN = 0.9999950000374997f; // 1/sqrt(1+1e-5)

    if (lane < 36) ssw[lane] = sw[lane];
    if (lane < 6) {
        sap[lane] = ap[lane];
        const float* posf = out1 + (size_t)((2 * BB) + b) * LL * 4 + 511 * 4;
        const float* posb = out1 + (size_t)((3 * BB) + b) * LL * 4 + 511 * 4;
        float v = lane < 3 ? posf[lane] : posb[lane - 3];
        float x = v * BN * pg[lane] + pb[lane];
        sph[lane] = fmaxf(x, 0.f);
    }
    __syncthreads();

    const float* F = out1 + (size_t)b * LL * 4;
    const float* Bw = out1 + (size_t)(BB + b) * LL * 4;

    float att[8];
    float mx = -1e30f;
#pragma unroll
    for (int k = 0; k < 8; ++k) {
        int l = lane + 64 * k;
        float4 f4 = *(const float4*)(F + l * 4);
        float4 b4 = *(const float4*)(Bw + l * 4);
        float r0 = f4.x, r1 = f4.y, r2 = f4.z, r3 = b4.x, r4 = b4.y, r5 = b4.z;
        float a = 0.f;
#pragma unroll
        for (int j = 0; j < 6; ++j) {
            float s = r0 * ssw[0 * 6 + j] + r1 * ssw[1 * 6 + j] + r2 * ssw[2 * 6 + j] +
                      r3 * ssw[3 * 6 + j] + r4 * ssw[4 * 6 + j] + r5 * ssw[5 * 6 + j];
            a += sap[j] * tanh_(s);
        }
        att[k] = a;
        mx = fmaxf(mx, a);
    }
#pragma unroll
    for (int off = 32; off; off >>= 1) mx = fmaxf(mx, __shfl_xor(mx, off));
    float e[8];
    float sum = 0.f;
#pragma unroll
    for (int k = 0; k < 8; ++k) { e[k] = exp2_(L2E * (att[k] - mx)); sum += e[k]; }
#pragma unroll
    for (int off = 32; off; off >>= 1) sum += __shfl_xor(sum, off);

    float acc[6] = {0.f, 0.f, 0.f, 0.f, 0.f, 0.f};
#pragma unroll
    for (int k = 0; k < 8; ++k) {
        int l = lane + 64 * k;
        float4 f4 = *(const float4*)(F + l * 4);
        float4 b4 = *(const float4*)(Bw + l * 4);
        acc[0] += e[k] * f4.x; acc[1] += e[k] * f4.y; acc[2] += e[k] * f4.z;
        acc[3] += e[k] * b4.x; acc[4] += e[k] * b4.y; acc[5] += e[k] * b4.z;
    }
#pragma unroll
    for (int j = 0; j < 6; ++j) {
#pragma unroll
        for (int off = 32; off; off >>= 1) acc[j] += __shfl_xor(acc[j], off);
    }
    if (lane < 6) scomb[lane] = acc[lane] / sum;
    __syncthreads();

    if (lane == 0) {
        float a[3];
#pragma unroll
        for (int j = 0; j < 3; ++j) {
            float t = pbias[j];
#pragma unroll
            for (int i = 0; i < 6; ++i) t += sph[i] * pw[j * 6 + i];
            a[j] = t;
        }
        float m = fmaxf(a[0], fmaxf(a[1], a[2]));
        float e0 = exp2_(L2E * (a[0] - m)), e1 = exp2_(L2E * (a[1] - m)), e2 = exp2_(L2E * (a[2] - m));
        float s = e0 + e1 + e2;
        float x0 = e0 / s, x1 = e1 / s, x2 = e2 / s;
        scomb[6] = x0; scomb[7] = x1; scomb[8] = x2;
        out[BB * 6 + b * 3 + 0] = x0;
        out[BB * 6 + b * 3 + 1] = x1;
        out[BB * 6 + b * 3 + 2] = x2;
    }
    __syncthreads();
    for (int o = lane; o < 128; o += 64) {
        float t = f1b[o];
#pragma unroll
        for (int k = 0; k < 9; ++k) t += scomb[k] * f1w[o * 9 + k];
        float x = t * BN * fg[o] + fb[o];
        sh[o] = fmaxf(x, 0.f);
    }
    __syncthreads();
    if (lane < 6) {
        float t = f2b[lane];
        for (int k = 0; k < 128; ++k) t += sh[k] * f2w[lane * 128 + k];
        sl[lane] = t;
    }
    __syncthreads();
    if (lane < 6) {
        float m = sl[0];
#pragma unroll
        for (int j = 1; j < 6; ++j) m = fmaxf(m, sl[j]);
        se[lane] = exp2_(L2E * (sl[lane] - m));
    }
    __syncthreads();
    if (lane < 6) {
        float s = se[0] + se[1] + se[2] + se[3] + se[4] + se[5];
        out[b * 6 + lane] = se[lane] / s;
    }
}

// ---------------------------------------------------------------------------
extern "C" void kernel_launch(void* const* d_in, const int* in_sizes, int n_in,
                              void* d_out, int out_size, void* d_ws, size_t ws_size,
                              hipStream_t stream)
{
    const int* wd  = (const int*)d_in[0];
    const int* pos = (const int*)d_in[1];
    const float* wd_emb  = (const float*)d_in[2];
    const float* pos_emb = (const float*)d_in[3];
    const float* cw2 = (const float*)d_in[4];  const float* cb2 = (const float*)d_in[5];
    const float* cw3 = (const float*)d_in[6];  const float* cb3 = (const float*)d_in[7];
    const float* cw4 = (const float*)d_in[8];  const float* cb4 = (const float*)d_in[9];
    const float* wd_wih0 = (const float*)d_in[10]; const float* wd_whh0 = (const float*)d_in[11];
    const float* wd_bih0 = (const float*)d_in[12]; const float* wd_bhh0 = (const float*)d_in[13];
    const float* wd_wih1 = (const float*)d_in[14]; const float* wd_whh1 = (const float*)d_in[15];
    const float* wd_bih1 = (const float*)d_in[16]; const float* wd_bhh1 = (const float*)d_in[17];
    const float* pos_wih0 = (const float*)d_in[18]; const float* pos_whh0 = (const float*)d_in[19];
    const float* pos_bih0 = (const float*)d_in[20]; const float* pos_bhh0 = (const float*)d_in[21];
    const float* pos_wih1 = (const float*)d_in[22]; const float* pos_whh1 = (const float*)d_in[23];
    const float* pos_bih1 = (const float*)d_in[24]; const float* pos_bhh1 = (const float*)d_in[25];
    const float* squish_w   = (const float*)d_in[26];
    const float* atten_proj = (const float*)d_in[27];
    const float* posfc_gamma = (const float*)d_in[28]; const float* posfc_beta = (const float*)d_in[29];
    const float* posfc_w = (const float*)d_in[30]; const float* posfc_b = (const float*)d_in[31];
    const float* fc1_w = (const float*)d_in[32]; const float* fc1_b = (const float*)d_in[33];
    const float* fc_gamma = (const float*)d_in[34]; const float* fc_beta = (const float*)d_in[35];
    const float* fc2_w = (const float*)d_in[36]; const float* fc2_b = (const float*)d_in[37];

    float* ws = (float*)d_ws;
    size_t off = 0;
    float* P = ws + off;      off += (size_t)VV * 72 + 8;
    float* gx = ws + off;     off += (size_t)4 * BB * LL * 9;
    float* out0 = ws + off;   off += (size_t)4 * BB * LL * 4;
    float* out1 = ws + off;   off += (size_t)4 * BB * LL * 4;
    float* Etab = ws + off;   off += 7200;
    float* beff = ws + off;   off += 32;
    float* Gp = ws + off;     off += PP * 18 + 14;
    float* wih1t = ws + off;  off += 216;
    float* bih1t = ws + off;  off += 40;

    k_build_tables<<<(8496 + 255) / 256, 256, 0, stream>>>(
        wd_wih0, wd_bih0, wd_bhh0, cw2, cb2, cw3, cb3, cw4, cb4,
        pos_emb, pos_wih0, pos_bih0, pos_bhh0,
        wd_wih1, wd_bih1, wd_bhh1, pos_wih1, pos_bih1, pos_bhh1,
        Etab, beff, Gp, wih1t, bih1t);
    {
        int vb = (VV + 3) / 4;
        int threads = vb * 8;
        k_build_P<<<(threads + 255) / 256, 256, 0, stream>>>(wd_emb, Etab, P);
    }
    k_gather<<<(2 * BB * LL + 255) / 256, 256, 0, stream>>>(wd, pos, P, beff, Gp, gx);
    k_scan0<<<2048, 64, 0, stream>>>(gx, out0, wd_whh0, wd_bhh0, pos_whh0, pos_bhh0);
    k_scan1<<<2048, 64, 0, stream>>>(out0, out1, wd_whh1, wd_bhh1, pos_whh1, pos_bhh1,
                                     wih1t, bih1t);
    k_head<<<BB, 64, 0, stream>>>(out1, squish_w, atten_proj, posfc_gamma, posfc_beta,
                                  posfc_w, posfc_b, fc1_w, fc1_b, fc_gamma, fc_beta,
                                  fc2_w, fc2_b, (float*)d_out);
}

// Round 10
// 105.988 us; speedup vs baseline: 1.4933x; 1.1221x over previous
//
#include <hip/hip_runtime.h>
#include <math.h>

#define BB 512   // batch
#define LL 512   // seq len
#define VV 23757 // wd vocab
#define PP 57    // pos vocab

#define L2E  1.4426950408889634f
#define NL2E (-1.4426950408889634f)
#define TL2E 2.8853900817779268f   // 2*log2(e)

__device__ __forceinline__ float rcp_(float x) { return __builtin_amdgcn_rcpf(x); }
__device__ __forceinline__ float exp2_(float x) { return __builtin_amdgcn_exp2f(x); }
__device__ __forceinline__ float tanh_(float x) { return 1.f - 2.f * rcp_(exp2_(TL2E * x) + 1.f); }

// gate scale: r,z -> -log2e ; n -> 2*log2e   (dg = dir*9 + g*3 + j)
__device__ __forceinline__ float gscale(int dg) {
    int g = (dg % 9) / 3;
    return g == 2 ? TL2E : NL2E;
}
__device__ __forceinline__ int is_rz(int dg) { return ((dg % 9) / 3) < 2; }

// quad_perm broadcast of lane K (0..2) within each 4-lane group, via DPP.
template <int K>
__device__ __forceinline__ float qb(float x) {
    constexpr int ctrl = K * 0x55;
    return __int_as_float(__builtin_amdgcn_update_dpp(0, __float_as_int(x), ctrl, 0xF, 0xF, true));
}

struct F3 { float r, z, n; };

// ---------------------------------------------------------------------------
// 1. Tables (prescaled for exp2-form gates), gate-major layouts.
// ---------------------------------------------------------------------------
__global__ void k_build_tables(const float* __restrict__ wd_wih0, const float* __restrict__ wd_bih0,
                               const float* __restrict__ wd_bhh0,
                               const float* __restrict__ cw2, const float* __restrict__ cb2,
                               const float* __restrict__ cw3, const float* __restrict__ cb3,
                               const float* __restrict__ cw4, const float* __restrict__ cb4,
                               const float* __restrict__ pos_emb,
                               const float* __restrict__ pos_wih0, const float* __restrict__ pos_bih0,
                               const float* __restrict__ pos_bhh0,
                               const float* __restrict__ wd_wih1, const float* __restrict__ wd_bih1,
                               const float* __restrict__ wd_bhh1,
                               const float* __restrict__ pos_wih1, const float* __restrict__ pos_bih1,
                               const float* __restrict__ pos_bhh1,
                               float* __restrict__ E, float* __restrict__ beff, float* __restrict__ Gp,
                               float* __restrict__ wih1t, float* __restrict__ bih1t)
{
    int idx = blockIdx.x * blockDim.x + threadIdx.x;
    if (idx < 7200) {
        int d  = idx % 100;
        int tt = (idx / 100) % 4;
        int dg = idx / 400;
        const float* wih = wd_wih0 + dg * 144;
        float acc = 0.f;
        if (tt == 0) {        // offset -2
            for (int o = 0; o < 48; ++o) acc += wih[96 + o] * cw4[o * 400 + d * 4 + 0];
        } else if (tt == 1) { // offset -1
            for (int o = 0; o < 48; ++o) acc += wih[o]      * cw2[o * 200 + d * 2 + 0];
            for (int o = 0; o < 48; ++o) acc += wih[48 + o] * cw3[o * 300 + d * 3 + 0];
            for (int o = 0; o < 48; ++o) acc += wih[96 + o] * cw4[o * 400 + d * 4 + 1];
        } else if (tt == 2) { // offset 0
            for (int o = 0; o < 48; ++o) acc += wih[o]      * cw2[o * 200 + d * 2 + 1];
            for (int o = 0; o < 48; ++o) acc += wih[48 + o] * cw3[o * 300 + d * 3 + 1];
            for (int o = 0; o < 48; ++o) acc += wih[96 + o] * cw4[o * 400 + d * 4 + 2];
        } else {              // offset +1
            for (int o = 0; o < 48; ++o) acc += wih[48 + o] * cw3[o * 300 + d * 3 + 2];
            for (int o = 0; o < 48; ++o) acc += wih[96 + o] * cw4[o * 400 + d * 4 + 3];
        }
        E[idx] = acc;
    } else if (idx < 7218) {
        int dg = idx - 7200;
        float acc = wd_bih0[dg];
        for (int o = 0; o < 48; ++o) acc += wd_wih0[dg * 144 + o]      * cb2[o];
        for (int o = 0; o < 48; ++o) acc += wd_wih0[dg * 144 + 48 + o] * cb3[o];
        for (int o = 0; o < 48; ++o) acc += wd_wih0[dg * 144 + 96 + o] * cb4[o];
        if (is_rz(dg)) acc += wd_bhh0[dg];
        beff[dg] = gscale(dg) * acc;
    } else if (idx < 8244) {
        int k = idx - 7218;
        int dg = k % 18;
        int p  = k / 18;
        float acc = pos_bih0[dg];
        for (int d = 0; d < 100; ++d) acc += pos_emb[p * 100 + d] * pos_wih0[dg * 100 + d];
        if (is_rz(dg)) acc += pos_bhh0[dg];
        Gp[p * 18 + dg] = gscale(dg) * acc;
    } else if (idx < 8352) {
        int i = idx - 8244; int dg = i / 6;
        wih1t[i] = gscale(dg) * wd_wih1[i];
    } else if (idx < 8370) {
        int dg = idx - 8352;
        float a = wd_bih1[dg] + (is_rz(dg) ? wd_bhh1[dg] : 0.f);
        bih1t[dg] = gscale(dg) * a;
    } else if (idx < 8478) {
        int i = idx - 8370; int dg = i / 6;
        wih1t[108 + i] = gscale(dg) * pos_wih1[i];
    } else if (idx < 8496) {
        int dg = idx - 8478;
        float a = pos_bih1[dg] + (is_rz(dg) ? pos_bhh1[dg] : 0.f);
        bih1t[18 + dg] = gscale(dg) * a;
    }
}

// ---------------------------------------------------------------------------
// 2. P~[v][tap][dg] = s_g * (wd_emb[v,:] . E[dg][tap][:])  (reg-blocked)
// ---------------------------------------------------------------------------
__global__ void __launch_bounds__(256) k_build_P(const float* __restrict__ wd_emb,
                                                 const float* __restrict__ E,
                                                 float* __restrict__ P)
{
    __shared__ float sEt[7200]; // [d][r], r = tt*18+dg
    for (int i = threadIdx.x; i < 7200; i += 256) {
        int d = i % 100, r = i / 100;
        int tt = r / 18, dg = r % 18;
        sEt[d * 72 + r] = E[dg * 400 + tt * 100 + d];
    }
    __syncthreads();
    int T = blockIdx.x * 256 + threadIdx.x;
    int og = T & 7;
    int vb = T >> 3;
    int v0 = vb * 4;
    if (v0 >= VV) return;
    int vlim = VV - 1 - v0;
    float gs[9];
#pragma unroll
    for (int k = 0; k < 9; ++k) {
        int dg = (og * 9 + k) % 18;
        gs[k] = ((dg % 9) / 3 == 2) ? TL2E : NL2E;
    }
    float acc[4][9];
#pragma unroll
    for (int vi = 0; vi < 4; ++vi)
#pragma unroll
        for (int k = 0; k < 9; ++k) acc[vi][k] = 0.f;

    const float* e0 = wd_emb + (size_t)v0 * 100;
#pragma unroll 1
    for (int d4 = 0; d4 < 25; ++d4) {
        float4 ev[4];
#pragma unroll
        for (int vi = 0; vi < 4; ++vi) {
            int vv = vi <= vlim ? vi : vlim;
            ev[vi] = *(const float4*)(e0 + vv * 100 + d4 * 4);
        }
#pragma unroll
        for (int dd = 0; dd < 4; ++dd) {
            int d = d4 * 4 + dd;
            const float* et = sEt + d * 72 + og * 9;
            float em0 = ((const float*)&ev[0])[dd];
            float em1 = ((const float*)&ev[1])[dd];
            float em2 = ((const float*)&ev[2])[dd];
            float em3 = ((const float*)&ev[3])[dd];
#pragma unroll
            for (int k = 0; k < 9; ++k) {
                float e = et[k];
                acc[0][k] = fmaf(em0, e, acc[0][k]);
                acc[1][k] = fmaf(em1, e, acc[1][k]);
                acc[2][k] = fmaf(em2, e, acc[2][k]);
                acc[3][k] = fmaf(em3, e, acc[3][k]);
            }
        }
    }
#pragma unroll
    for (int vi = 0; vi < 4; ++vi) {
        if (vi <= vlim) {
            float* p = P + (size_t)(v0 + vi) * 72 + og * 9;
#pragma unroll
            for (int k = 0; k < 9; ++k) p[k] = gs[k] * acc[vi][k];
        }
    }
}

// ---------------------------------------------------------------------------
// 3. Gather: one thread per (branch,b,l); vectorized dwordx3 stores.
//    gx layout: [(branch*2+dir)*BB + b][l][j][g]
// ---------------------------------------------------------------------------
__global__ void k_gather(const int* __restrict__ wd, const int* __restrict__ pos,
                         const float* __restrict__ P, const float* __restrict__ beff,
                         const float* __restrict__ Gp, float* __restrict__ gx)
{
    int idx = blockIdx.x * blockDim.x + threadIdx.x;
    if (idx >= 2 * BB * LL) return;
    int branch = idx >= BB * LL;
    int k = idx - branch * BB * LL;
    int l = k % LL, b = k / LL;

    float v[18];
    if (!branch) {
#pragma unroll
        for (int i = 0; i < 18; ++i) v[i] = beff[i];
        const int* row = wd + b * LL;
#pragma unroll
        for (int t = 0; t < 4; ++t) {
            int ll = l - 2 + t;
            if (ll >= 0 && ll < LL) {
                const float* p = P + (long)row[ll] * 72 + t * 18;
#pragma unroll
                for (int i = 0; i < 18; ++i) v[i] += p[i];
            }
        }
    } else {
        const float* p = Gp + pos[k] * 18;
#pragma unroll
        for (int i = 0; i < 18; ++i) v[i] = p[i];
    }
    float* g0 = gx + ((long)(branch * 2 + 0) * BB + b) * (LL * 9) + l * 9;
    float* g1 = gx + ((long)(branch * 2 + 1) * BB + b) * (LL * 9) + l * 9;
#pragma unroll
    for (int j = 0; j < 3; ++j) {
        F3 w0 = {v[j], v[3 + j], v[6 + j]};
        F3 w1 = {v[9 + j], v[12 + j], v[15 + j]};
        *(F3*)(g0 + j * 3) = w0;
        *(F3*)(g1 + j * 3) = w1;
    }
}

// ---------------------------------------------------------------------------
// 4. Scan layer 0. R=32 real/chunk, W=40 warm -> 72 steps.
//    Warm: 5 groups of 8, no LDS/barrier. Real: 4 groups of 8 + flush.
//    Clamped virtual byte-offset prefetch. 2048 blocks.
// ---------------------------------------------------------------------------
__global__ void __launch_bounds__(64) k_scan0(
        const float* __restrict__ gx0, float* __restrict__ out,
        const float* __restrict__ whhA, const float* __restrict__ bhhA,
        const float* __restrict__ whhB, const float* __restrict__ bhhB)
{
    __shared__ float lbuf[8 * 81];
    int lane = threadIdx.x;
    int c = lane >> 2, sub = lane & 3;   // c = chunk 0..15
    int jj = sub < 3 ? sub : 2;
    int chain = blockIdx.x;
    int branch = chain >> 10;
    int rem = chain & 1023;
    int dir = rem >> 9;

    const float* whh = (branch ? whhB : whhA) + dir * 27;
    const float* bhh = (branch ? bhhB : bhhA) + dir * 9;

    float wr0 = NL2E * whh[jj * 3 + 0], wr1 = NL2E * whh[jj * 3 + 1], wr2 = NL2E * whh[jj * 3 + 2];
    float wz0 = NL2E * whh[(3 + jj) * 3 + 0], wz1 = NL2E * whh[(3 + jj) * 3 + 1], wz2 = NL2E * whh[(3 + jj) * 3 + 2];
    float wn0 = TL2E * whh[(6 + jj) * 3 + 0], wn1 = TL2E * whh[(6 + jj) * 3 + 1], wn2 = TL2E * whh[(6 + jj) * 3 + 2];
    float bnx = TL2E * bhh[6 + jj];

    const int OMAX = 511 * 36;
    int t0 = c * 32 - 40;
    int sstp = dir ? -36 : 36;
    int off = dir ? (OMAX - t0 * 36) : t0 * 36;   // virtual; clamp per use
    const char* gxc = (const char*)gx0 + (size_t)chain * (LL * 36) + jj * 12;

    F3 buf[8];
#pragma unroll
    for (int s = 0; s < 8; ++s) {
        int a = min(max(off, 0), OMAX);
        buf[s] = *(const F3*)(gxc + a);
        off += sstp;
    }

    char* ob = (char*)out + (size_t)chain * (LL * 16) + sub * 32;
    int thr = 40 - c * 32;   // h forced 0 while step-index < thr

    float h = 0.f;
    // ---- warm: 5 groups of 8 (no LDS, no barrier) ----
    for (int g = 0; g < 5; ++g) {
#pragma unroll
        for (int s = 0; s < 8; ++s) {
            F3 gv = buf[s];
            int a = min(max(off, 0), OMAX);
            buf[s] = *(const F3*)(gxc + a);
            off += sstp;

            float h0 = qb<0>(h), h1 = qb<1>(h), h2 = qb<2>(h);
            float sr = fmaf(wr0, h0, fmaf(wr1, h1, fmaf(wr2, h2, gv.r)));
            float sz = fmaf(wz0, h0, fmaf(wz1, h1, fmaf(wz2, h2, gv.z)));
            float gn3 = fmaf(wn0, h0, fmaf(wn1, h1, fmaf(wn2, h2, bnx)));
            float r = rcp_(1.f + exp2_(sr));
            float z = rcp_(1.f + exp2_(sz));
            float u = rcp_(1.f + exp2_(fmaf(r, gn3, gv.n)));
            float n = fmaf(-2.f, u, 1.f);
            float hn = fmaf(z, h - n, n);
            int i = g * 8 + s;
            h = (i >= thr) ? hn : 0.f;
        }
    }
    // ---- real: 4 groups of 8 + flush ----
    for (int g = 0; g < 4; ++g) {
#pragma unroll
        for (int s = 0; s < 8; ++s) {
            F3 gv = buf[s];
            int a = min(max(off, 0), OMAX);
            buf[s] = *(const F3*)(gxc + a);
            off += sstp;

            float h0 = qb<0>(h), h1 = qb<1>(h), h2 = qb<2>(h);
            float sr = fmaf(wr0, h0, fmaf(wr1, h1, fmaf(wr2, h2, gv.r)));
            float sz = fmaf(wz0, h0, fmaf(wz1, h1, fmaf(wz2, h2, gv.z)));
            float gn3 = fmaf(wn0, h0, fmaf(wn1, h1, fmaf(wn2, h2, bnx)));
            float r = rcp_(1.f + exp2_(sr));
            float z = rcp_(1.f + exp2_(sz));
            float u = rcp_(1.f + exp2_(fmaf(r, gn3, gv.n)));
            float n = fmaf(-2.f, u, 1.f);
            h = fmaf(z, h - n, n);
            lbuf[s * 81 + c * 5 + sub] = h;
        }
        __syncthreads();
        {
            int tbase = t0 + 40 + g * 8;
            int l0 = dir ? (LL - 1 - tbase - 7) : tbase;
#pragma unroll
            for (int i = 0; i < 2; ++i) {
                int lofs = sub * 2 + i;
                int s = dir ? (7 - lofs) : lofs;
                float4 vv;
                vv.x = lbuf[s * 81 + c * 5 + 0];
                vv.y = lbuf[s * 81 + c * 5 + 1];
                vv.z = lbuf[s * 81 + c * 5 + 2];
                vv.w = lbuf[s * 81 + c * 5 + 3];
                *(float4*)(ob + (size_t)l0 * 16 + i * 16) = vv;
            }
        }
        __syncthreads();
    }
}

// ---------------------------------------------------------------------------
// 5. Scan layer 1 with fused input projection. R=32, W=40, 2048 blocks.
// ---------------------------------------------------------------------------
__global__ void __launch_bounds__(64) k_scan1(
        const float* __restrict__ out0, float* __restrict__ out1,
        const float* __restrict__ whhA, const float* __restrict__ bhhA,
        const float* __restrict__ whhB, const float* __restrict__ bhhB,
        const float* __restrict__ wih1t, const float* __restrict__ bih1t)
{
    __shared__ float lbuf[8 * 81];
    int lane = threadIdx.x;
    int c = lane >> 2, sub = lane & 3;
    int jj = sub < 3 ? sub : 2;
    int chain = blockIdx.x;
    int branch = chain >> 10;
    int rem = chain & 1023;
    int dir = rem >> 9;
    int b = rem & 511;

    const float* whh = (branch ? whhB : whhA) + dir * 27;
    const float* bhh = (branch ? bhhB : bhhA) + dir * 9;

    float wr0 = NL2E * whh[jj * 3 + 0], wr1 = NL2E * whh[jj * 3 + 1], wr2 = NL2E * whh[jj * 3 + 2];
    float wz0 = NL2E * whh[(3 + jj) * 3 + 0], wz1 = NL2E * whh[(3 + jj) * 3 + 1], wz2 = NL2E * whh[(3 + jj) * 3 + 2];
    float wn0 = TL2E * whh[(6 + jj) * 3 + 0], wn1 = TL2E * whh[(6 + jj) * 3 + 1], wn2 = TL2E * whh[(6 + jj) * 3 + 2];
    float bnx = TL2E * bhh[6 + jj];

    const float* Wb = wih1t + branch * 108;
    const float* Bv = bih1t + branch * 18;
    int dgr = dir * 9 + jj, dgz = dgr + 3, dgn = dgr + 6;
    float Wr[6], Wz[6], Wn[6];
#pragma unroll
    for (int q = 0; q < 6; ++q) {
        Wr[q] = Wb[dgr * 6 + q];
        Wz[q] = Wb[dgz * 6 + q];
        Wn[q] = Wb[dgn * 6 + q];
    }
    float Br = Bv[dgr], Bz = Bv[dgz], Bn = Bv[dgn];

    const char* o0c = (const char*)((const float4*)out0 + (size_t)((branch * 2 + 0) * BB + b) * LL);
    const char* o1c = (const char*)((const float4*)out0 + (size_t)((branch * 2 + 1) * BB + b) * LL);

    const int OMAX = 511 * 16;
    int t0 = c * 32 - 40;
    int sstp = dir ? -16 : 16;
    int off = dir ? (OMAX - t0 * 16) : t0 * 16;

    float4 bf[8], bg[8];
#pragma unroll
    for (int s = 0; s < 8; ++s) {
        int a = min(max(off, 0), OMAX);
        bf[s] = *(const float4*)(o0c + a);
        bg[s] = *(const float4*)(o1c + a);
        off += sstp;
    }

    char* ob = (char*)out1 + (size_t)chain * (LL * 16) + sub * 32;
    int thr = 40 - c * 32;

    float h = 0.f;
    // ---- warm ----
    for (int g = 0; g < 5; ++g) {
#pragma unroll
        for (int s = 0; s < 8; ++s) {
            float4 f4 = bf[s], q4 = bg[s];
            int a = min(max(off, 0), OMAX);
            bf[s] = *(const float4*)(o0c + a);
            bg[s] = *(const float4*)(o1c + a);
            off += sstp;

            float gr = fmaf(f4.x, Wr[0], fmaf(f4.y, Wr[1], fmaf(f4.z, Wr[2], Br)));
            gr = fmaf(q4.x, Wr[3], fmaf(q4.y, Wr[4], fmaf(q4.z, Wr[5], gr)));
            float gz = fmaf(f4.x, Wz[0], fmaf(f4.y, Wz[1], fmaf(f4.z, Wz[2], Bz)));
            gz = fmaf(q4.x, Wz[3], fmaf(q4.y, Wz[4], fmaf(q4.z, Wz[5], gz)));
            float gn = fmaf(f4.x, Wn[0], fmaf(f4.y, Wn[1], fmaf(f4.z, Wn[2], Bn)));
            gn = fmaf(q4.x, Wn[3], fmaf(q4.y, Wn[4], fmaf(q4.z, Wn[5], gn)));

            float h0 = qb<0>(h), h1 = qb<1>(h), h2 = qb<2>(h);
            float sr = fmaf(wr0, h0, fmaf(wr1, h1, fmaf(wr2, h2, gr)));
            float sz = fmaf(wz0, h0, fmaf(wz1, h1, fmaf(wz2, h2, gz)));
            float gn3 = fmaf(wn0, h0, fmaf(wn1, h1, fmaf(wn2, h2, bnx)));
            float r = rcp_(1.f + exp2_(sr));
            float z = rcp_(1.f + exp2_(sz));
            float u = rcp_(1.f + exp2_(fmaf(r, gn3, gn)));
            float n = fmaf(-2.f, u, 1.f);
            float hn = fmaf(z, h - n, n);
            int i = g * 8 + s;
            h = (i >= thr) ? hn : 0.f;
        }
    }
    // ---- real ----
    for (int g = 0; g < 4; ++g) {
#pragma unroll
        for (int s = 0; s < 8; ++s) {
            float4 f4 = bf[s], q4 = bg[s];
            int a = min(max(off, 0), OMAX);
            bf[s] = *(const float4*)(o0c + a);
            bg[s] = *(const float4*)(o1c + a);
            off += sstp;

            float gr = fmaf(f4.x, Wr[0], fmaf(f4.y, Wr[1], fmaf(f4.z, Wr[2], Br)));
            gr = fmaf(q4.x, Wr[3], fmaf(q4.y, Wr[4], fmaf(q4.z, Wr[5], gr)));
            float gz = fmaf(f4.x, Wz[0], fmaf(f4.y, Wz[1], fmaf(f4.z, Wz[2], Bz)));
            gz = fmaf(q4.x, Wz[3], fmaf(q4.y, Wz[4], fmaf(q4.z, Wz[5], gz)));
            float gn = fmaf(f4.x, Wn[0], fmaf(f4.y, Wn[1], fmaf(f4.z, Wn[2], Bn)));
            gn = fmaf(q4.x, Wn[3], fmaf(q4.y, Wn[4], fmaf(q4.z, Wn[5], gn)));

            float h0 = qb<0>(h), h1 = qb<1>(h), h2 = qb<2>(h);
            float sr = fmaf(wr0, h0, fmaf(wr1, h1, fmaf(wr2, h2, gr)));
            float sz = fmaf(wz0, h0, fmaf(wz1, h1, fmaf(wz2, h2, gz)));
            float gn3 = fmaf(wn0, h0, fmaf(wn1, h1, fmaf(wn2, h2, bnx)));
            float r = rcp_(1.f + exp2_(sr));
            float z = rcp_(1.f + exp2_(sz));
            float u = rcp_(1.f + exp2_(fmaf(r, gn3, gn)));
            float n = fmaf(-2.f, u, 1.f);
            h = fmaf(z, h - n, n);
            lbuf[s * 81 + c * 5 + sub] = h;
        }
        __syncthreads();
        {
            int tbase = t0 + 40 + g * 8;
            int l0 = dir ? (LL - 1 - tbase - 7) : tbase;
#pragma unroll
            for (int i = 0; i < 2; ++i) {
                int lofs = sub * 2 + i;
                int s = dir ? (7 - lofs) : lofs;
                float4 vv;
                vv.x = lbuf[s * 81 + c * 5 + 0];
                vv.y = lbuf[s * 81 + c * 5 + 1];
                vv.z = lbuf[s * 81 + c * 5 + 2];
                vv.w = lbuf[s * 81 + c * 5 + 3];
                *(float4*)(ob + (size_t)l0 * 16 + i * 16) = vv;
            }
        }
        __syncthreads();
    }
}

// ---------------------------------------------------------------------------
// 6. Fused head: attention over wd_out + posfc/auxi + fc1/fc2 softmax.
// ---------------------------------------------------------------------------
__global__ void k_head(const float* __restrict__ out1,
                       const float* __restrict__ sw, const float* __restrict__ ap,
                       const float* __restrict__ pg, const float* __restrict__ pb,
                       const float* __restrict__ pw, const float* __restrict__ pbias,
                       const float* __restrict__ f1w, const float* __restrict__ f1b,
                       const float* __restrict__ fg, const float* __restrict__ fb,
                       const float* __restrict__ f2w, const float* __restrict__ f2b,
                       float* __restrict__ out)
{
    int b = blockIdx.x;
    int lane = threadIdx.x;
    __shared__ float ssw[36], sap[6], sph[6], scomb[9], sh[128], sl[6], se[6];
    const float BN = 0.9999950000374997f; // 1/sqrt(1+1e-5)

    if (lane < 36) ssw[lane] = sw[lane];
    if (lane < 6) {
        sap[lane] = ap[lane];
        const float* posf = out1 + (size_t)((2 * BB) + b) * LL * 4 + 511 * 4;
        const float* posb = out1 + (size_t)((3 * BB) + b) * LL * 4 + 511 * 4;
        float v = lane < 3 ? posf[lane] : posb[lane - 3];
        float x = v * BN * pg[lane] + pb[lane];
        sph[lane] = fmaxf(x, 0.f);
    }
    __syncthreads();

    const float* F = out1 + (size_t)b * LL * 4;
    const float* Bw = out1 + (size_t)(BB + b) * LL * 4;

    float att[8];
    float mx = -1e30f;
#pragma unroll
    for (int k = 0; k < 8; ++k) {
        int l = lane + 64 * k;
        float4 f4 = *(const float4*)(F + l * 4);
        float4 b4 = *(const float4*)(Bw + l * 4);
        float r0 = f4.x, r1 = f4.y, r2 = f4.z, r3 = b4.x, r4 = b4.y, r5 = b4.z;
        float a = 0.f;
#pragma unroll
        for (int j = 0; j < 6; ++j) {
            float s = r0 * ssw[0 * 6 + j] + r1 * ssw[1 * 6 + j] + r2 * ssw[2 * 6 + j] +
                      r3 * ssw[3 * 6 + j] + r4 * ssw[4 * 6 + j] + r5 * ssw[5 * 6 + j];
            a += sap[j] * tanh_(s);
        }
        att[k] = a;
        mx = fmaxf(mx, a);
    }
#pragma unroll
    for (int off = 32; off; off >>= 1) mx = fmaxf(mx, __shfl_xor(mx, off));
    float e[8];
    float sum = 0.f;
#pragma unroll
    for (int k = 0; k < 8; ++k) { e[k] = exp2_(L2E * (att[k] - mx)); sum += e[k]; }
#pragma unroll
    for (int off = 32; off; off >>= 1) sum += __shfl_xor(sum, off);

    float acc[6] = {0.f, 0.f, 0.f, 0.f, 0.f, 0.f};
#pragma unroll
    for (int k = 0; k < 8; ++k) {
        int l = lane + 64 * k;
        float4 f4 = *(const float4*)(F + l * 4);
        float4 b4 = *(const float4*)(Bw + l * 4);
        acc[0] += e[k] * f4.x; acc[1] += e[k] * f4.y; acc[2] += e[k] * f4.z;
        acc[3] += e[k] * b4.x; acc[4] += e[k] * b4.y; acc[5] += e[k] * b4.z;
    }
#pragma unroll
    for (int j = 0; j < 6; ++j) {
#pragma unroll
        for (int off = 32; off; off >>= 1) acc[j] += __shfl_xor(acc[j], off);
    }
    if (lane < 6) scomb[lane] = acc[lane] / sum;
    __syncthreads();

    if (lane == 0) {
        float a[3];
#pragma unroll
        for (int j = 0; j < 3; ++j) {
            float t = pbias[j];
#pragma unroll
            for (int i = 0; i < 6; ++i) t += sph[i] * pw[j * 6 + i];
            a[j] = t;
        }
        float m = fmaxf(a[0], fmaxf(a[1], a[2]));
        float e0 = exp2_(L2E * (a[0] - m)), e1 = exp2_(L2E * (a[1] - m)), e2 = exp2_(L2E * (a[2] - m));
        float s = e0 + e1 + e2;
        float x0 = e0 / s, x1 = e1 / s, x2 = e2 / s;
        scomb[6] = x0; scomb[7] = x1; scomb[8] = x2;
        out[BB * 6 + b * 3 + 0] = x0;
        out[BB * 6 + b * 3 + 1] = x1;
        out[BB * 6 + b * 3 + 2] = x2;
    }
    __syncthreads();
    for (int o = lane; o < 128; o += 64) {
        float t = f1b[o];
#pragma unroll
        for (int k = 0; k < 9; ++k) t += scomb[k] * f1w[o * 9 + k];
        float x = t * BN * fg[o] + fb[o];
        sh[o] = fmaxf(x, 0.f);
    }
    __syncthreads();
    if (lane < 6) {
        float t = f2b[lane];
        for (int k = 0; k < 128; ++k) t += sh[k] * f2w[lane * 128 + k];
        sl[lane] = t;
    }
    __syncthreads();
    if (lane < 6) {
        float m = sl[0];
#pragma unroll
        for (int j = 1; j < 6; ++j) m = fmaxf(m, sl[j]);
        se[lane] = exp2_(L2E * (sl[lane] - m));
    }
    __syncthreads();
    if (lane < 6) {
        float s = se[0] + se[1] + se[2] + se[3] + se[4] + se[5];
        out[b * 6 + lane] = se[lane] / s;
    }
}

// ---------------------------------------------------------------------------
extern "C" void kernel_launch(void* const* d_in, const int* in_sizes, int n_in,
                              void* d_out, int out_size, void* d_ws, size_t ws_size,
                              hipStream_t stream)
{
    const int* wd  = (const int*)d_in[0];
    const int* pos = (const int*)d_in[1];
    const float* wd_emb  = (const float*)d_in[2];
    const float* pos_emb = (const float*)d_in[3];
    const float* cw2 = (const float*)d_in[4];  const float* cb2 = (const float*)d_in[5];
    const float* cw3 = (const float*)d_in[6];  const float* cb3 = (const float*)d_in[7];
    const float* cw4 = (const float*)d_in[8];  const float* cb4 = (const float*)d_in[9];
    const float* wd_wih0 = (const float*)d_in[10]; const float* wd_whh0 = (const float*)d_in[11];
    const float* wd_bih0 = (const float*)d_in[12]; const float* wd_bhh0 = (const float*)d_in[13];
    const float* wd_wih1 = (const float*)d_in[14]; const float* wd_whh1 = (const float*)d_in[15];
    const float* wd_bih1 = (const float*)d_in[16]; const float* wd_bhh1 = (const float*)d_in[17];
    const float* pos_wih0 = (const float*)d_in[18]; const float* pos_whh0 = (const float*)d_in[19];
    const float* pos_bih0 = (const float*)d_in[20]; const float* pos_bhh0 = (const float*)d_in[21];
    const float* pos_wih1 = (const float*)d_in[22]; const float* pos_whh1 = (const float*)d_in[23];
    const float* pos_bih1 = (const float*)d_in[24]; const float* pos_bhh1 = (const float*)d_in[25];
    const float* squish_w   = (const float*)d_in[26];
    const float* atten_proj = (const float*)d_in[27];
    const float* posfc_gamma = (const float*)d_in[28]; const float* posfc_beta = (const float*)d_in[29];
    const float* posfc_w = (const float*)d_in[30]; const float* posfc_b = (const float*)d_in[31];
    const float* fc1_w = (const float*)d_in[32]; const float* fc1_b = (const float*)d_in[33];
    const float* fc_gamma = (const float*)d_in[34]; const float* fc_beta = (const float*)d_in[35];
    const float* fc2_w = (const float*)d_in[36]; const float* fc2_b = (const float*)d_in[37];

    float* ws = (float*)d_ws;
    size_t off = 0;
    float* P = ws + off;      off += (size_t)VV * 72 + 8;
    float* gx = ws + off;     off += (size_t)4 * BB * LL * 9;
    float* out0 = ws + off;   off += (size_t)4 * BB * LL * 4;
    float* out1 = ws + off;   off += (size_t)4 * BB * LL * 4;
    float* Etab = ws + off;   off += 7200;
    float* beff = ws + off;   off += 32;
    float* Gp = ws + off;     off += PP * 18 + 14;
    float* wih1t = ws + off;  off += 216;
    float* bih1t = ws + off;  off += 40;

    k_build_tables<<<(8496 + 255) / 256, 256, 0, stream>>>(
        wd_wih0, wd_bih0, wd_bhh0, cw2, cb2, cw3, cb3, cw4, cb4,
        pos_emb, pos_wih0, pos_bih0, pos_bhh0,
        wd_wih1, wd_bih1, wd_bhh1, pos_wih1, pos_bih1, pos_bhh1,
        Etab, beff, Gp, wih1t, bih1t);
    {
        int vb = (VV + 3) / 4;
        int threads = vb * 8;
        k_build_P<<<(threads + 255) / 256, 256, 0, stream>>>(wd_emb, Etab, P);
    }
    k_gather<<<(2 * BB * LL + 255) / 256, 256, 0, stream>>>(wd, pos, P, beff, Gp, gx);
    k_scan0<<<2048, 64, 0, stream>>>(gx, out0, wd_whh0, wd_bhh0, pos_whh0, pos_bhh0);
    k_scan1<<<2048, 64, 0, stream>>>(out0, out1, wd_whh1, wd_bhh1, pos_whh1, pos_bhh1,
                                     wih1t, bih1t);
    k_head<<<BB, 64, 0, stream>>>(out1, squish_w, atten_proj, posfc_gamma, posfc_beta,
                                  posfc_w, posfc_b, fc1_w, fc1_b, fc_gamma, fc_beta,
                                  fc2_w, fc2_b, (float*)d_out);
}